// Round 2
// baseline (203.567 us; speedup 1.0000x reference)
//
#include <hip/hip_runtime.h>
#include <hip/hip_bf16.h>

#define BATCH 2
#define SEQ 2048
#define DMODEL 768
#define NHEADS 12
#define NKV 4
#define DHEAD 64
#define WIN 512
#define GLB 64
#define ROWS (BATCH * SEQ)  // 4096

typedef short short8 __attribute__((ext_vector_type(8)));
typedef float f32x4 __attribute__((ext_vector_type(4)));

// fp32 -> bf16 bits, round-to-nearest-even (finite inputs only)
__device__ inline short f2bs(float f) {
    unsigned u = __float_as_uint(f);
    return (short)((u + 0x7fffu + ((u >> 16) & 1u)) >> 16);
}

// ---------------------------------------------------------------------------
// All four weight transposes in one launch: w[768,N] fp32 -> wT[N,768] bf16.
// ---------------------------------------------------------------------------
__global__ __launch_bounds__(256) void transp_all(
    const float* __restrict__ wq, const float* __restrict__ wk,
    const float* __restrict__ wv, const float* __restrict__ wo,
    short* __restrict__ wqkvT, short* __restrict__ woT) {
    __shared__ float t[32][33];
    int bid = blockIdx.x;
    const float* src; short* dst; int N;
    if (bid < 576)      { src = wq; dst = wqkvT; N = DMODEL; }
    else if (bid < 768) { src = wk; dst = wqkvT + DMODEL * DMODEL; N = 256; bid -= 576; }
    else if (bid < 960) { src = wv; dst = wqkvT + (DMODEL + 256) * DMODEL; N = 256; bid -= 768; }
    else                { src = wo; dst = woT; N = DMODEL; bid -= 960; }
    const int ntx = N >> 5;
    const int k0 = (bid / ntx) << 5, n0 = (bid % ntx) << 5;
    const int x = threadIdx.x & 31, y = threadIdx.x >> 5;
#pragma unroll
    for (int i = 0; i < 32; i += 8)
        t[y + i][x] = src[(long)(k0 + y + i) * N + n0 + x];
    __syncthreads();
#pragma unroll
    for (int i = 0; i < 32; i += 8)
        dst[(long)(n0 + y + i) * DMODEL + k0 + x] = f2bs(t[x][y + i]);
}

// ---------------------------------------------------------------------------
// V^T prep, PANELED: out_v (B,NKV,SEQ,64) fp32 ->
// Vt[bkv][t>>6][d][t&63] bf16 (each 64-key panel = 8 KB contiguous).
// ---------------------------------------------------------------------------
__global__ __launch_bounds__(256) void vtransp(const float* __restrict__ in,
                                               short* __restrict__ out) {
    __shared__ float t[32][33];
    const long bkv = blockIdx.z;
    const float* ip = in + bkv * SEQ * DHEAD;
    short* op = out + bkv * DHEAD * SEQ;
    const int t0 = blockIdx.x * 32, d0 = blockIdx.y * 32;
    const int x = threadIdx.x & 31, y = threadIdx.x >> 5;
#pragma unroll
    for (int i = 0; i < 32; i += 8)
        t[y + i][x] = ip[(long)(t0 + y + i) * DHEAD + d0 + x];
    __syncthreads();
    const int pan = t0 >> 6, tin = t0 & 63;  // uniform for x<32
#pragma unroll
    for (int i = 0; i < 32; i += 8)
        op[(long)pan * 4096 + (d0 + y + i) * 64 + tin + x] = f2bs(t[x][y + i]);
}

// ---------------------------------------------------------------------------
// MFMA GEMM (TN): C = A[M,K] @ Bt[N,K]^T, fp32 accumulate.
// MODE 0: plain fp32 C.  MODE 1: 3-way split (Q / K cache / V cache).
// ---------------------------------------------------------------------------
#define LST 40

template <typename TA, int MODE>
__global__ __launch_bounds__(256) void gemm_tn(const TA* __restrict__ A,
                                               const short* __restrict__ Bt,
                                               float* __restrict__ Cq,
                                               float* __restrict__ Ck,
                                               float* __restrict__ Cv,
                                               int M, int N, int K) {
    __shared__ short As_[128 * LST];
    __shared__ short Bs_[128 * LST];
    const int tid = threadIdx.x;
    const int lane = tid & 63, w = tid >> 6;
    const int m_ = lane & 15, quad = lane >> 4;
    const int wm = w >> 1, wn = w & 1;
    const long bm = (long)blockIdx.y * 128, bn = (long)blockIdx.x * 128;
    const int sr = tid >> 1, sh = (tid & 1) * 16;

    f32x4 acc[4][4];
#pragma unroll
    for (int i = 0; i < 4; ++i)
#pragma unroll
        for (int j = 0; j < 4; ++j) acc[i][j] = (f32x4){0.f, 0.f, 0.f, 0.f};

    for (int k0 = 0; k0 < K; k0 += 32) {
        short av[16], bv[16];
        if (sizeof(TA) == 4) {
            const float* ap = (const float*)A + (bm + sr) * K + k0 + sh;
            float ff[16];
#pragma unroll
            for (int i = 0; i < 4; ++i) *(float4*)&ff[4 * i] = ((const float4*)ap)[i];
#pragma unroll
            for (int i = 0; i < 16; ++i) av[i] = f2bs(ff[i]);
        } else {
            const short* ap = (const short*)A + (bm + sr) * K + k0 + sh;
            *(uint4*)&av[0] = ((const uint4*)ap)[0];
            *(uint4*)&av[8] = ((const uint4*)ap)[1];
        }
        {
            const short* bp = Bt + (bn + sr) * K + k0 + sh;
            *(uint4*)&bv[0] = ((const uint4*)bp)[0];
            *(uint4*)&bv[8] = ((const uint4*)bp)[1];
        }
        __syncthreads();
        short* ad = &As_[sr * LST + sh];
        short* bd = &Bs_[sr * LST + sh];
#pragma unroll
        for (int i = 0; i < 4; ++i) {
            ((uint2*)ad)[i] = ((uint2*)av)[i];
            ((uint2*)bd)[i] = ((uint2*)bv)[i];
        }
        __syncthreads();

        short8 af[4], bf[4];
#pragma unroll
        for (int i = 0; i < 4; ++i)
            af[i] = *(const short8*)&As_[(wm * 64 + i * 16 + m_) * LST + quad * 8];
#pragma unroll
        for (int j = 0; j < 4; ++j)
            bf[j] = *(const short8*)&Bs_[(wn * 64 + j * 16 + m_) * LST + quad * 8];
#pragma unroll
        for (int i = 0; i < 4; ++i)
#pragma unroll
            for (int j = 0; j < 4; ++j)
                acc[i][j] = __builtin_amdgcn_mfma_f32_16x16x32_bf16(af[i], bf[j], acc[i][j], 0, 0, 0);
    }

#pragma unroll
    for (int i = 0; i < 4; ++i) {
        const int row0 = (int)bm + wm * 64 + i * 16 + quad * 4;
#pragma unroll
        for (int j = 0; j < 4; ++j) {
            const int col = (int)bn + wn * 64 + j * 16 + m_;
#pragma unroll
            for (int r = 0; r < 4; ++r) {
                const int rw = row0 + r;
                const float val = acc[i][j][r];
                if (MODE == 1) {
                    if (col < DMODEL) {
                        Cq[(long)rw * DMODEL + col] = val;
                    } else {
                        const int c2 = col - DMODEL;
                        const int hh = (c2 >> 6) & 3, d = c2 & 63;
                        long oidx = (((long)((rw >> 11) * NKV + hh) * SEQ + (rw & (SEQ - 1))) << 6) | d;
                        ((c2 >> 8) ? Cv : Ck)[oidx] = val;
                    }
                } else {
                    Cq[(long)rw * N + col] = val;
                }
            }
        }
    }
}

// ---------------------------------------------------------------------------
// RoPE: Q fp32 -> bf16 Qb (1/8 scale); K fp32 in place + bf16 copy Kb.
// ---------------------------------------------------------------------------
__global__ void rope_f(const float* __restrict__ Qi, short* __restrict__ Qb,
                       float* Kc, short* Kb) {
    int tid = blockIdx.x * blockDim.x + threadIdx.x;
    int j = tid & 31;
    int head = (tid >> 5) & 15;
    int row = tid >> 9;
    int t = row & (SEQ - 1);
    int b = row >> 11;
    float inv = expf(-(float)j * 0.2878231366f);
    float s, c;
    sincosf((float)t * inv, &s, &c);
    if (head < NHEADS) {
        const float* p = Qi + (long)row * DMODEL + head * DHEAD;
        short* q = Qb + (long)row * DMODEL + head * DHEAD;
        float x1 = p[j], x2 = p[j + 32];
        q[j] = f2bs((x1 * c - x2 * s) * 0.125f);
        q[j + 32] = f2bs((x2 * c + x1 * s) * 0.125f);
    } else {
        const long off = ((long)(b * NKV + (head - NHEADS)) * SEQ + t) << 6;
        float* p = Kc + off;
        float x1 = p[j], x2 = p[j + 32];
        float y1 = x1 * c - x2 * s, y2 = x2 * c + x1 * s;
        p[j] = y1;
        p[j + 32] = y2;
        Kb[off + j] = f2bs(y1);
        Kb[off + j + 32] = f2bs(y2);
    }
}

// ---------------------------------------------------------------------------
// Flash v8: staged (coalesced) K/V like v6, but with the two measured stalls
// removed:
//  (1) T2 XOR-swizzle (linear stride 64 shorts, c16 ^= row&7) -> bank
//      conflicts ~0, LDS 50.7->44 KB (3 blocks/CU capacity).
//  (2) T4 counted-vmcnt pipeline: raw s_barrier + lgkmcnt(0) only (never
//      vmcnt(0) at barriers), prefetch depth 2 tiles: stage_load(i+2) issued
//      at iter i, consumed by stage_write at iter i+1 -> one full tile of
//      compute covers global latency; loads stay in flight across barriers.
//  (3) T5 setprio around MFMA clusters.
// Safety: all frag ds_reads complete before each barrier (lgkmcnt(0));
// stage_write always targets the opposite buffer parity from the one read
// this iteration; every barrier is preceded by lgkmcnt(0) so ds_writes are
// visible to other waves. __syncthreads is NOT used (it drains vmcnt(0)).
// ---------------------------------------------------------------------------
__global__ __launch_bounds__(384, 4) void flash6(
    const short* __restrict__ Qb, const short* __restrict__ Kb,
    const short* __restrict__ Vt, short* __restrict__ ATT) {
    __shared__ short Kbuf[2][64 * 64];
    __shared__ short Vbuf[2][64 * 64];
    __shared__ short Pl[6][16 * 64];
    const int tid = threadIdx.x;
    const int w = tid >> 6, lane = tid & 63;
    const int m_ = lane & 15, quad = lane >> 4;
    const int sw = m_ & 7;
    const int bkv = blockIdx.x >> 6;
    const int t0 = (63 - (blockIdx.x & 63)) << 5;   // heavy blocks first
    const int b = bkv >> 2, kvh = bkv & 3;
    const int h = kvh * 3 + (w >> 1);
    const int qg = w & 1;
    const int trw = t0 + (qg << 4);
    const int tq = trw + m_;       // this lane's q-row
    const long kgb = ((long)bkv * SEQ) << 6;        // Kb base (shorts)
    const long vgb = (long)bkv * SEQ * DHEAD;       // Vt base (shorts)

    // Q B-frags
    const short* qp = Qb + (long)(b * SEQ + tq) * DMODEL + h * DHEAD + quad * 8;
    const short8 qf0 = *(const short8*)qp;
    const short8 qf1 = *(const short8*)(qp + 32);

    f32x4 of[4];
#pragma unroll
    for (int i = 0; i < 4; ++i) of[i] = (f32x4){0.f, 0.f, 0.f, 0.f};
    float mr = -1e30f, lr = 0.f;

    int wlo = t0 - (WIN - 1);      // FIRST row's window floor
    if (wlo < GLB) wlo = GLB;
    wlo &= ~63;
    const int nwin = (t0 + 31 >= wlo) ? (((t0 + 31 - wlo) >> 6) + 1) : 0;
    const int ntile = 1 + nwin;
    auto kb_of = [&](int j) { return (j == 0) ? 0 : (wlo + ((j - 1) << 6)); };

    // staging: 1024 uint4 items (K 512 | V 512); 384 thr x <=3 rounds
    uint4 sreg[3];
    int sidx[3], scnt = 0;
#pragma unroll
    for (int r = 0; r < 3; ++r) {
        int idx = tid + r * 384;
        if (idx < 1024) sidx[scnt++] = idx;
    }
    auto stage_load = [&](int kb) {
        const short* kp = Kb + kgb + ((long)kb << 6);
        const short* vp = Vt + vgb + (((long)kb >> 6) << 12);
        for (int r = 0; r < scnt; ++r) {
            int idx = sidx[r];
            sreg[r] = (idx < 512) ? *(const uint4*)(kp + (idx << 3))
                                  : *(const uint4*)(vp + ((idx - 512) << 3));
        }
    };
    auto stage_write = [&](int bs) {
        for (int r = 0; r < scnt; ++r) {
            int idx = sidx[r];
            int i2 = idx & 511;
            int row = i2 >> 3, c = i2 & 7;
            int off = row * 64 + ((c ^ (row & 7)) << 3);   // T2 XOR swizzle
            if (idx < 512) *(uint4*)&Kbuf[bs][off] = sreg[r];
            else           *(uint4*)&Vbuf[bs][off] = sreg[r];
        }
    };

    stage_load(kb_of(0));
    stage_write(0);
    if (ntile > 1) stage_load(kb_of(1));
    asm volatile("s_waitcnt lgkmcnt(0)" ::: "memory");
    __builtin_amdgcn_s_barrier();
    __builtin_amdgcn_sched_barrier(0);

    for (int tI = 0; tI < ntile; ++tI) {
        const int kb = kb_of(tI);
        const int bs = tI & 1;

        // frags from LDS (swizzled reads; conflict-free)
        short8 kf[8], vf[8];
#pragma unroll
        for (int st = 0; st < 4; ++st)
#pragma unroll
            for (int hh = 0; hh < 2; ++hh)
                kf[st * 2 + hh] = *(const short8*)&Kbuf[bs][(st * 16 + m_) * 64 + (((hh * 4 + quad) ^ sw) << 3)];
#pragma unroll
        for (int dt = 0; dt < 4; ++dt)
#pragma unroll
            for (int kh = 0; kh < 2; ++kh)
                vf[dt * 2 + kh] = *(const short8*)&Vbuf[bs][(dt * 16 + m_) * 64 + (((kh * 4 + quad) ^ sw) << 3)];

        // S^T = K Q^T
        f32x4 s[4];
        __builtin_amdgcn_s_setprio(1);
#pragma unroll
        for (int st = 0; st < 4; ++st) {
            f32x4 a = (f32x4){0.f, 0.f, 0.f, 0.f};
            a = __builtin_amdgcn_mfma_f32_16x16x32_bf16(kf[st * 2 + 0], qf0, a, 0, 0, 0);
            a = __builtin_amdgcn_mfma_f32_16x16x32_bf16(kf[st * 2 + 1], qf1, a, 0, 0, 0);
            s[st] = a;
        }
        __builtin_amdgcn_s_setprio(0);

        const bool fully = (kb + 63 <= trw) &&
                           ((kb >= trw + 16 - WIN) || (kb + 63 < GLB) || (trw + 15 < GLB));
        if (!fully) {
#pragma unroll
            for (int st = 0; st < 4; ++st) {
#pragma unroll
                for (int r = 0; r < 4; ++r) {
                    const int key = kb + st * 16 + quad * 4 + r;
                    const bool ok = (key <= tq) && ((key > tq - WIN) || (key < GLB) || (tq < GLB));
                    if (!ok) s[st][r] = -1e30f;
                }
            }
        }

        // online softmax (per-lane; 2 shuffles across quad replicas)
        float tm = -1e30f;
#pragma unroll
        for (int st = 0; st < 4; ++st)
#pragma unroll
            for (int r = 0; r < 4; ++r) tm = fmaxf(tm, s[st][r]);
        tm = fmaxf(tm, __shfl_xor(tm, 16, 64));
        tm = fmaxf(tm, __shfl_xor(tm, 32, 64));
        // defer-rescale: alpha==1 exactly when max doesn't grow -> skip pass
        if (!__all(tm <= mr)) {
            const float mnew = fmaxf(mr, tm);
            const float alpha = __expf(mr - mnew);
            mr = mnew;
            lr *= alpha;
#pragma unroll
            for (int dt = 0; dt < 4; ++dt)
#pragma unroll
                for (int r = 0; r < 4; ++r) of[dt][r] *= alpha;
        }
        float rs = 0.f;
#pragma unroll
        for (int st = 0; st < 4; ++st) {
            float p0 = __expf(s[st][0] - mr);
            float p1 = __expf(s[st][1] - mr);
            float p2 = __expf(s[st][2] - mr);
            float p3 = __expf(s[st][3] - mr);
            rs += (p0 + p1) + (p2 + p3);
            union { short sh[4]; unsigned long long u; } pk;
            pk.sh[0] = f2bs(p0); pk.sh[1] = f2bs(p1);
            pk.sh[2] = f2bs(p2); pk.sh[3] = f2bs(p3);
            // swizzled 8B write: row m_, short-col st*16+quad*4
            *(unsigned long long*)&Pl[w][m_ * 64 + (((st * 2 + (quad >> 1)) ^ sw) << 3) + ((quad & 1) << 2)] = pk.u;
        }
        rs += __shfl_xor(rs, 16, 64);
        rs += __shfl_xor(rs, 32, 64);
        lr += rs;

        // P^T B-frags via per-wave LDS (same wave writes+reads: no barrier)
        short8 pf[2];
#pragma unroll
        for (int kh = 0; kh < 2; ++kh)
            pf[kh] = *(const short8*)&Pl[w][m_ * 64 + (((kh * 4 + quad) ^ sw) << 3)];

        // O^T += V^T P^T
        __builtin_amdgcn_s_setprio(1);
#pragma unroll
        for (int dt = 0; dt < 4; ++dt) {
            of[dt] = __builtin_amdgcn_mfma_f32_16x16x32_bf16(vf[dt * 2 + 0], pf[0], of[dt], 0, 0, 0);
            of[dt] = __builtin_amdgcn_mfma_f32_16x16x32_bf16(vf[dt * 2 + 1], pf[1], of[dt], 0, 0, 0);
        }
        __builtin_amdgcn_s_setprio(0);

        // pipeline: write next tile (loads issued one iter ago -> covered),
        // then issue loads two tiles ahead; barrier WITHOUT vmcnt drain.
        if (tI + 1 < ntile) stage_write((tI + 1) & 1);
        if (tI + 2 < ntile) stage_load(kb_of(tI + 2));
        asm volatile("s_waitcnt lgkmcnt(0)" ::: "memory");
        __builtin_amdgcn_s_barrier();
        __builtin_amdgcn_sched_barrier(0);
    }

    // epilogue
    const float inv = 1.0f / lr;
    short* op = ATT + (long)(b * SEQ + tq) * DMODEL + h * DHEAD + quad * 4;
#pragma unroll
    for (int dt = 0; dt < 4; ++dt) {
        union { short sh[4]; unsigned long long u; } pk;
#pragma unroll
        for (int r = 0; r < 4; ++r) pk.sh[r] = f2bs(of[dt][r] * inv);
        *(unsigned long long*)(op + dt * 16) = pk.u;
    }
}

// ---------------------------------------------------------------------------
extern "C" void kernel_launch(void* const* d_in, const int* in_sizes, int n_in,
                              void* d_out, int out_size, void* d_ws, size_t ws_size,
                              hipStream_t stream) {
    const float* x = (const float*)d_in[0];
    const float* wq = (const float*)d_in[1];
    const float* wk = (const float*)d_in[2];
    const float* wv = (const float*)d_in[3];
    const float* wo = (const float*)d_in[4];
    float* out = (float*)d_out;
    float* out_k = out + (long)ROWS * DMODEL;
    float* out_v = out_k + (long)BATCH * NKV * SEQ * DHEAD;

    // ws (shorts), 11.125 MiB: region A: wqkvT -> Qb -> ATTb (sequential lifetimes)
    short* regA = (short*)d_ws;
    short* wqkvT = regA;
    short* Qb = regA;
    short* ATTb = regA;
    short* woT = regA + (long)ROWS * DMODEL;
    short* KbB = woT + (long)DMODEL * DMODEL;
    short* VtB = KbB + (long)BATCH * NKV * SEQ * DHEAD;

    transp_all<<<1536, 256, 0, stream>>>(wq, wk, wv, wo, wqkvT, woT);
    gemm_tn<float, 1><<<dim3((DMODEL + 2 * NKV * DHEAD) / 128, ROWS / 128), 256, 0, stream>>>(
        x, wqkvT, out, out_k, out_v, ROWS, DMODEL + 2 * NKV * DHEAD, DMODEL);
    rope_f<<<(ROWS * 16 * 32) / 256, 256, 0, stream>>>(out, Qb, out_k, KbB);
    vtransp<<<dim3(SEQ / 32, DHEAD / 32, BATCH * NKV), 256, 0, stream>>>(out_v, VtB);
    flash6<<<BATCH * NKV * (SEQ / 32), 384, 0, stream>>>(Qb, KbB, VtB, ATTb);
    gemm_tn<short, 0><<<dim3(DMODEL / 128, ROWS / 128), 256, 0, stream>>>(
        ATTb, woT, out, nullptr, nullptr, ROWS, DMODEL, DMODEL);
}

// Round 3
// 171.176 us; speedup vs baseline: 1.1892x; 1.1892x over previous
//
#include <hip/hip_runtime.h>
#include <hip/hip_bf16.h>

#define BATCH 2
#define SEQ 2048
#define DMODEL 768
#define NHEADS 12
#define NKV 4
#define DHEAD 64
#define WIN 512
#define GLB 64
#define ROWS (BATCH * SEQ)  // 4096

typedef short short8 __attribute__((ext_vector_type(8)));
typedef float f32x4 __attribute__((ext_vector_type(4)));

// fp32 -> bf16 bits, round-to-nearest-even (finite inputs only)
__device__ inline short f2bs(float f) {
    unsigned u = __float_as_uint(f);
    return (short)((u + 0x7fffu + ((u >> 16) & 1u)) >> 16);
}

// async global->LDS DMA, 16B/lane: LDS dest = wave-uniform base + lane*16.
__device__ inline void cp16(const short* g, short* l) {
    __builtin_amdgcn_global_load_lds(
        (const __attribute__((address_space(1))) unsigned int*)g,
        (__attribute__((address_space(3))) unsigned int*)l, 16, 0, 0);
}

// ---------------------------------------------------------------------------
// All four weight transposes in one launch: w[768,N] fp32 -> wT[N,768] bf16.
// ---------------------------------------------------------------------------
__global__ __launch_bounds__(256) void transp_all(
    const float* __restrict__ wq, const float* __restrict__ wk,
    const float* __restrict__ wv, const float* __restrict__ wo,
    short* __restrict__ wqkvT, short* __restrict__ woT) {
    __shared__ float t[32][33];
    int bid = blockIdx.x;
    const float* src; short* dst; int N;
    if (bid < 576)      { src = wq; dst = wqkvT; N = DMODEL; }
    else if (bid < 768) { src = wk; dst = wqkvT + DMODEL * DMODEL; N = 256; bid -= 576; }
    else if (bid < 960) { src = wv; dst = wqkvT + (DMODEL + 256) * DMODEL; N = 256; bid -= 768; }
    else                { src = wo; dst = woT; N = DMODEL; bid -= 960; }
    const int ntx = N >> 5;
    const int k0 = (bid / ntx) << 5, n0 = (bid % ntx) << 5;
    const int x = threadIdx.x & 31, y = threadIdx.x >> 5;
#pragma unroll
    for (int i = 0; i < 32; i += 8)
        t[y + i][x] = src[(long)(k0 + y + i) * N + n0 + x];
    __syncthreads();
#pragma unroll
    for (int i = 0; i < 32; i += 8)
        dst[(long)(n0 + y + i) * DMODEL + k0 + x] = f2bs(t[x][y + i]);
}

// ---------------------------------------------------------------------------
// V^T prep, PANELED: out_v (B,NKV,SEQ,64) fp32 ->
// Vt[bkv][t>>6][d][t&63] bf16 (each 64-key panel = 8 KB contiguous).
// ---------------------------------------------------------------------------
__global__ __launch_bounds__(256) void vtransp(const float* __restrict__ in,
                                               short* __restrict__ out) {
    __shared__ float t[32][33];
    const long bkv = blockIdx.z;
    const float* ip = in + bkv * SEQ * DHEAD;
    short* op = out + bkv * DHEAD * SEQ;
    const int t0 = blockIdx.x * 32, d0 = blockIdx.y * 32;
    const int x = threadIdx.x & 31, y = threadIdx.x >> 5;
#pragma unroll
    for (int i = 0; i < 32; i += 8)
        t[y + i][x] = ip[(long)(t0 + y + i) * DHEAD + d0 + x];
    __syncthreads();
    const int pan = t0 >> 6, tin = t0 & 63;  // uniform for x<32
#pragma unroll
    for (int i = 0; i < 32; i += 8)
        op[(long)pan * 4096 + (d0 + y + i) * 64 + tin + x] = f2bs(t[x][y + i]);
}

// ---------------------------------------------------------------------------
// MFMA GEMM (TN): C = A[M,K] @ Bt[N,K]^T, fp32 accumulate.
// MODE 0: plain fp32 C.  MODE 1: 3-way split (Q / K cache / V cache).
// ---------------------------------------------------------------------------
#define LST 40

template <typename TA, int MODE>
__global__ __launch_bounds__(256) void gemm_tn(const TA* __restrict__ A,
                                               const short* __restrict__ Bt,
                                               float* __restrict__ Cq,
                                               float* __restrict__ Ck,
                                               float* __restrict__ Cv,
                                               int M, int N, int K) {
    __shared__ short As_[128 * LST];
    __shared__ short Bs_[128 * LST];
    const int tid = threadIdx.x;
    const int lane = tid & 63, w = tid >> 6;
    const int m_ = lane & 15, quad = lane >> 4;
    const int wm = w >> 1, wn = w & 1;
    const long bm = (long)blockIdx.y * 128, bn = (long)blockIdx.x * 128;
    const int sr = tid >> 1, sh = (tid & 1) * 16;

    f32x4 acc[4][4];
#pragma unroll
    for (int i = 0; i < 4; ++i)
#pragma unroll
        for (int j = 0; j < 4; ++j) acc[i][j] = (f32x4){0.f, 0.f, 0.f, 0.f};

    for (int k0 = 0; k0 < K; k0 += 32) {
        short av[16], bv[16];
        if (sizeof(TA) == 4) {
            const float* ap = (const float*)A + (bm + sr) * K + k0 + sh;
            float ff[16];
#pragma unroll
            for (int i = 0; i < 4; ++i) *(float4*)&ff[4 * i] = ((const float4*)ap)[i];
#pragma unroll
            for (int i = 0; i < 16; ++i) av[i] = f2bs(ff[i]);
        } else {
            const short* ap = (const short*)A + (bm + sr) * K + k0 + sh;
            *(uint4*)&av[0] = ((const uint4*)ap)[0];
            *(uint4*)&av[8] = ((const uint4*)ap)[1];
        }
        {
            const short* bp = Bt + (bn + sr) * K + k0 + sh;
            *(uint4*)&bv[0] = ((const uint4*)bp)[0];
            *(uint4*)&bv[8] = ((const uint4*)bp)[1];
        }
        __syncthreads();
        short* ad = &As_[sr * LST + sh];
        short* bd = &Bs_[sr * LST + sh];
#pragma unroll
        for (int i = 0; i < 4; ++i) {
            ((uint2*)ad)[i] = ((uint2*)av)[i];
            ((uint2*)bd)[i] = ((uint2*)bv)[i];
        }
        __syncthreads();

        short8 af[4], bf[4];
#pragma unroll
        for (int i = 0; i < 4; ++i)
            af[i] = *(const short8*)&As_[(wm * 64 + i * 16 + m_) * LST + quad * 8];
#pragma unroll
        for (int j = 0; j < 4; ++j)
            bf[j] = *(const short8*)&Bs_[(wn * 64 + j * 16 + m_) * LST + quad * 8];
#pragma unroll
        for (int i = 0; i < 4; ++i)
#pragma unroll
            for (int j = 0; j < 4; ++j)
                acc[i][j] = __builtin_amdgcn_mfma_f32_16x16x32_bf16(af[i], bf[j], acc[i][j], 0, 0, 0);
    }

#pragma unroll
    for (int i = 0; i < 4; ++i) {
        const int row0 = (int)bm + wm * 64 + i * 16 + quad * 4;
#pragma unroll
        for (int j = 0; j < 4; ++j) {
            const int col = (int)bn + wn * 64 + j * 16 + m_;
#pragma unroll
            for (int r = 0; r < 4; ++r) {
                const int rw = row0 + r;
                const float val = acc[i][j][r];
                if (MODE == 1) {
                    if (col < DMODEL) {
                        Cq[(long)rw * DMODEL + col] = val;
                    } else {
                        const int c2 = col - DMODEL;
                        const int hh = (c2 >> 6) & 3, d = c2 & 63;
                        long oidx = (((long)((rw >> 11) * NKV + hh) * SEQ + (rw & (SEQ - 1))) << 6) | d;
                        ((c2 >> 8) ? Cv : Ck)[oidx] = val;
                    }
                } else {
                    Cq[(long)rw * N + col] = val;
                }
            }
        }
    }
}

// ---------------------------------------------------------------------------
// RoPE: Q fp32 -> bf16 Qb (1/8 scale); K fp32 in place + bf16 copy Kb.
// ---------------------------------------------------------------------------
__global__ void rope_f(const float* __restrict__ Qi, short* __restrict__ Qb,
                       float* Kc, short* Kb) {
    int tid = blockIdx.x * blockDim.x + threadIdx.x;
    int j = tid & 31;
    int head = (tid >> 5) & 15;
    int row = tid >> 9;
    int t = row & (SEQ - 1);
    int b = row >> 11;
    float inv = expf(-(float)j * 0.2878231366f);
    float s, c;
    sincosf((float)t * inv, &s, &c);
    if (head < NHEADS) {
        const float* p = Qi + (long)row * DMODEL + head * DHEAD;
        short* q = Qb + (long)row * DMODEL + head * DHEAD;
        float x1 = p[j], x2 = p[j + 32];
        q[j] = f2bs((x1 * c - x2 * s) * 0.125f);
        q[j + 32] = f2bs((x2 * c + x1 * s) * 0.125f);
    } else {
        const long off = ((long)(b * NKV + (head - NHEADS)) * SEQ + t) << 6;
        float* p = Kc + off;
        float x1 = p[j], x2 = p[j + 32];
        float y1 = x1 * c - x2 * s, y2 = x2 * c + x1 * s;
        p[j] = y1;
        p[j + 32] = y2;
        Kb[off + j] = f2bs(y1);
        Kb[off + j + 32] = f2bs(y2);
    }
}

// ---------------------------------------------------------------------------
// Flash v9: staged K/V via async global_load_lds DMA (no VGPR round-trip, no
// runtime-indexed register arrays -> no scratch: v6/v8's ~20 MB hidden HBM
// write/fetch of spill traffic is gone). XOR-swizzle kept by PRE-SWIZZLING
// the per-lane GLOBAL source address (linear LDS dest, same involution on
// the ds_read side). 1-tile prefetch: issue 16x1KB DMAs for tile i+1 (2-3
// per wave) at iter-i top; a full tile of MFMA+softmax covers the latency;
// vmcnt(0) + raw s_barrier at iter end (no lgkm drain needed -- staging no
// longer touches LDS counters; no sched_barrier(0) anywhere).
// ---------------------------------------------------------------------------
__global__ __launch_bounds__(384) void flash6(
    const short* __restrict__ Qb, const short* __restrict__ Kb,
    const short* __restrict__ Vt, short* __restrict__ ATT) {
    __shared__ short Kbuf[2][64 * 64];
    __shared__ short Vbuf[2][64 * 64];
    __shared__ short Pl[6][16 * 64];
    const int tid = threadIdx.x;
    const int w = tid >> 6, lane = tid & 63;
    const int m_ = lane & 15, quad = lane >> 4;
    const int sw = m_ & 7;
    const int bkv = blockIdx.x >> 6;
    const int t0 = (63 - (blockIdx.x & 63)) << 5;   // heavy blocks first
    const int b = bkv >> 2, kvh = bkv & 3;
    const int h = kvh * 3 + (w >> 1);
    const int qg = w & 1;
    const int trw = t0 + (qg << 4);
    const int tq = trw + m_;       // this lane's q-row
    const long kgb = ((long)bkv * SEQ) << 6;        // Kb base (shorts)
    const long vgb = (long)bkv * SEQ * DHEAD;       // Vt base (shorts)

    // per-lane inverse-swizzled source offset (shorts): row=lane>>3 within
    // 8-row chunk, 16B-group = (lane&7) ^ (lane>>3). LDS dest is linear.
    const int soff = ((lane >> 3) << 6) + (((lane & 7) ^ (lane >> 3)) << 3);

    // Q B-frags
    const short* qp = Qb + (long)(b * SEQ + tq) * DMODEL + h * DHEAD + quad * 8;
    const short8 qf0 = *(const short8*)qp;
    const short8 qf1 = *(const short8*)(qp + 32);

    f32x4 of[4];
#pragma unroll
    for (int i = 0; i < 4; ++i) of[i] = (f32x4){0.f, 0.f, 0.f, 0.f};
    float mr = -1e30f, lr = 0.f;

    int wlo = t0 - (WIN - 1);      // FIRST row's window floor
    if (wlo < GLB) wlo = GLB;
    wlo &= ~63;
    const int nwin = (t0 + 31 >= wlo) ? (((t0 + 31 - wlo) >> 6) + 1) : 0;
    const int ntile = 1 + nwin;
    auto kb_of = [&](int j) { return (j == 0) ? 0 : (wlo + ((j - 1) << 6)); };

    // 16 chunks of 1KB (K rows 8c..8c+7 | V d-rows 8c..8c+7); wave w takes
    // chunks {w, w+6, w+12} -- wave-uniform control, no register arrays.
    auto stage = [&](int kb, int bs) {
#pragma unroll
        for (int r = 0; r < 3; ++r) {
            const int ch = w + 6 * r;
            if (ch < 8) {
                cp16(Kb + kgb + ((long)(kb + (ch << 3)) << 6) + soff,
                     &Kbuf[bs][ch << 9]);
            } else if (ch < 16) {
                const int cv = ch - 8;
                cp16(Vt + vgb + (((long)kb >> 6) << 12) + (cv << 9) + soff,
                     &Vbuf[bs][cv << 9]);
            }
        }
    };

    stage(kb_of(0), 0);
    asm volatile("s_waitcnt vmcnt(0)" ::: "memory");
    asm volatile("s_barrier" ::: "memory");

    for (int tI = 0; tI < ntile; ++tI) {
        const int kb = kb_of(tI);
        const int bs = tI & 1;
        if (tI + 1 < ntile) stage(kb_of(tI + 1), bs ^ 1);

        // frags from LDS (swizzled reads; conflict-light)
        short8 kf[8], vf[8];
#pragma unroll
        for (int st = 0; st < 4; ++st)
#pragma unroll
            for (int hh = 0; hh < 2; ++hh)
                kf[st * 2 + hh] = *(const short8*)&Kbuf[bs][(st * 16 + m_) * 64 + (((hh * 4 + quad) ^ sw) << 3)];
#pragma unroll
        for (int dt = 0; dt < 4; ++dt)
#pragma unroll
            for (int kh = 0; kh < 2; ++kh)
                vf[dt * 2 + kh] = *(const short8*)&Vbuf[bs][(dt * 16 + m_) * 64 + (((kh * 4 + quad) ^ sw) << 3)];

        // S^T = K Q^T
        f32x4 s[4];
        __builtin_amdgcn_s_setprio(1);
#pragma unroll
        for (int st = 0; st < 4; ++st) {
            f32x4 a = (f32x4){0.f, 0.f, 0.f, 0.f};
            a = __builtin_amdgcn_mfma_f32_16x16x32_bf16(kf[st * 2 + 0], qf0, a, 0, 0, 0);
            a = __builtin_amdgcn_mfma_f32_16x16x32_bf16(kf[st * 2 + 1], qf1, a, 0, 0, 0);
            s[st] = a;
        }
        __builtin_amdgcn_s_setprio(0);

        const bool fully = (kb + 63 <= trw) &&
                           ((kb >= trw + 16 - WIN) || (kb + 63 < GLB) || (trw + 15 < GLB));
        if (!fully) {
#pragma unroll
            for (int st = 0; st < 4; ++st) {
#pragma unroll
                for (int r = 0; r < 4; ++r) {
                    const int key = kb + st * 16 + quad * 4 + r;
                    const bool ok = (key <= tq) && ((key > tq - WIN) || (key < GLB) || (tq < GLB));
                    if (!ok) s[st][r] = -1e30f;
                }
            }
        }

        // online softmax (per-lane; 2 shuffles across quad replicas)
        float tm = -1e30f;
#pragma unroll
        for (int st = 0; st < 4; ++st)
#pragma unroll
            for (int r = 0; r < 4; ++r) tm = fmaxf(tm, s[st][r]);
        tm = fmaxf(tm, __shfl_xor(tm, 16, 64));
        tm = fmaxf(tm, __shfl_xor(tm, 32, 64));
        // defer-rescale: alpha==1 exactly when max doesn't grow -> skip pass
        if (!__all(tm <= mr)) {
            const float mnew = fmaxf(mr, tm);
            const float alpha = __expf(mr - mnew);
            mr = mnew;
            lr *= alpha;
#pragma unroll
            for (int dt = 0; dt < 4; ++dt)
#pragma unroll
                for (int r = 0; r < 4; ++r) of[dt][r] *= alpha;
        }
        float rs = 0.f;
#pragma unroll
        for (int st = 0; st < 4; ++st) {
            float p0 = __expf(s[st][0] - mr);
            float p1 = __expf(s[st][1] - mr);
            float p2 = __expf(s[st][2] - mr);
            float p3 = __expf(s[st][3] - mr);
            rs += (p0 + p1) + (p2 + p3);
            union { short sh[4]; unsigned long long u; } pk;
            pk.sh[0] = f2bs(p0); pk.sh[1] = f2bs(p1);
            pk.sh[2] = f2bs(p2); pk.sh[3] = f2bs(p3);
            // swizzled 8B write: row m_, short-col st*16+quad*4
            *(unsigned long long*)&Pl[w][m_ * 64 + (((st * 2 + (quad >> 1)) ^ sw) << 3) + ((quad & 1) << 2)] = pk.u;
        }
        rs += __shfl_xor(rs, 16, 64);
        rs += __shfl_xor(rs, 32, 64);
        lr += rs;

        // P^T B-frags via per-wave LDS (same wave writes+reads: no barrier)
        short8 pf[2];
#pragma unroll
        for (int kh = 0; kh < 2; ++kh)
            pf[kh] = *(const short8*)&Pl[w][m_ * 64 + (((kh * 4 + quad) ^ sw) << 3)];

        // O^T += V^T P^T
        __builtin_amdgcn_s_setprio(1);
#pragma unroll
        for (int dt = 0; dt < 4; ++dt) {
            of[dt] = __builtin_amdgcn_mfma_f32_16x16x32_bf16(vf[dt * 2 + 0], pf[0], of[dt], 0, 0, 0);
            of[dt] = __builtin_amdgcn_mfma_f32_16x16x32_bf16(vf[dt * 2 + 1], pf[1], of[dt], 0, 0, 0);
        }
        __builtin_amdgcn_s_setprio(0);

        // drain prefetch DMAs + barrier (skip after last tile)
        if (tI + 1 < ntile) {
            asm volatile("s_waitcnt vmcnt(0)" ::: "memory");
            asm volatile("s_barrier" ::: "memory");
        }
    }

    // epilogue
    const float inv = 1.0f / lr;
    short* op = ATT + (long)(b * SEQ + tq) * DMODEL + h * DHEAD + quad * 4;
#pragma unroll
    for (int dt = 0; dt < 4; ++dt) {
        union { short sh[4]; unsigned long long u; } pk;
#pragma unroll
        for (int r = 0; r < 4; ++r) pk.sh[r] = f2bs(of[dt][r] * inv);
        *(unsigned long long*)(op + dt * 16) = pk.u;
    }
}

// ---------------------------------------------------------------------------
extern "C" void kernel_launch(void* const* d_in, const int* in_sizes, int n_in,
                              void* d_out, int out_size, void* d_ws, size_t ws_size,
                              hipStream_t stream) {
    const float* x = (const float*)d_in[0];
    const float* wq = (const float*)d_in[1];
    const float* wk = (const float*)d_in[2];
    const float* wv = (const float*)d_in[3];
    const float* wo = (const float*)d_in[4];
    float* out = (float*)d_out;
    float* out_k = out + (long)ROWS * DMODEL;
    float* out_v = out_k + (long)BATCH * NKV * SEQ * DHEAD;

    // ws (shorts), 11.125 MiB: region A: wqkvT -> Qb -> ATTb (sequential lifetimes)
    short* regA = (short*)d_ws;
    short* wqkvT = regA;
    short* Qb = regA;
    short* ATTb = regA;
    short* woT = regA + (long)ROWS * DMODEL;
    short* KbB = woT + (long)DMODEL * DMODEL;
    short* VtB = KbB + (long)BATCH * NKV * SEQ * DHEAD;

    transp_all<<<1536, 256, 0, stream>>>(wq, wk, wv, wo, wqkvT, woT);
    gemm_tn<float, 1><<<dim3((DMODEL + 2 * NKV * DHEAD) / 128, ROWS / 128), 256, 0, stream>>>(
        x, wqkvT, out, out_k, out_v, ROWS, DMODEL + 2 * NKV * DHEAD, DMODEL);
    rope_f<<<(ROWS * 16 * 32) / 256, 256, 0, stream>>>(out, Qb, out_k, KbB);
    vtransp<<<dim3(SEQ / 32, DHEAD / 32, BATCH * NKV), 256, 0, stream>>>(out_v, VtB);
    flash6<<<BATCH * NKV * (SEQ / 32), 384, 0, stream>>>(Qb, KbB, VtB, ATTb);
    gemm_tn<short, 0><<<dim3(DMODEL / 128, ROWS / 128), 256, 0, stream>>>(
        ATTb, woT, out, nullptr, nullptr, ROWS, DMODEL, DMODEL);
}

// Round 4
// 161.245 us; speedup vs baseline: 1.2625x; 1.0616x over previous
//
#include <hip/hip_runtime.h>
#include <hip/hip_bf16.h>

#define BATCH 2
#define SEQ 2048
#define DMODEL 768
#define NHEADS 12
#define NKV 4
#define DHEAD 64
#define WIN 512
#define GLB 64
#define ROWS (BATCH * SEQ)  // 4096

typedef short short8 __attribute__((ext_vector_type(8)));
typedef float f32x4 __attribute__((ext_vector_type(4)));

// fp32 -> bf16 bits, round-to-nearest-even (finite inputs only)
__device__ inline short f2bs(float f) {
    unsigned u = __float_as_uint(f);
    return (short)((u + 0x7fffu + ((u >> 16) & 1u)) >> 16);
}

// async global->LDS DMA, 16B/lane: LDS dest = wave-uniform base + lane*16.
__device__ inline void cp16(const short* g, short* l) {
    __builtin_amdgcn_global_load_lds(
        (const __attribute__((address_space(1))) unsigned int*)g,
        (__attribute__((address_space(3))) unsigned int*)l, 16, 0, 0);
}

// ---------------------------------------------------------------------------
// All four weight transposes in one launch: w[768,N] fp32 -> wT[N,768] bf16.
// ---------------------------------------------------------------------------
__global__ __launch_bounds__(256) void transp_all(
    const float* __restrict__ wq, const float* __restrict__ wk,
    const float* __restrict__ wv, const float* __restrict__ wo,
    short* __restrict__ wqkvT, short* __restrict__ woT) {
    __shared__ float t[32][33];
    int bid = blockIdx.x;
    const float* src; short* dst; int N;
    if (bid < 576)      { src = wq; dst = wqkvT; N = DMODEL; }
    else if (bid < 768) { src = wk; dst = wqkvT + DMODEL * DMODEL; N = 256; bid -= 576; }
    else if (bid < 960) { src = wv; dst = wqkvT + (DMODEL + 256) * DMODEL; N = 256; bid -= 768; }
    else                { src = wo; dst = woT; N = DMODEL; bid -= 960; }
    const int ntx = N >> 5;
    const int k0 = (bid / ntx) << 5, n0 = (bid % ntx) << 5;
    const int x = threadIdx.x & 31, y = threadIdx.x >> 5;
#pragma unroll
    for (int i = 0; i < 32; i += 8)
        t[y + i][x] = src[(long)(k0 + y + i) * N + n0 + x];
    __syncthreads();
#pragma unroll
    for (int i = 0; i < 32; i += 8)
        dst[(long)(n0 + y + i) * DMODEL + k0 + x] = f2bs(t[x][y + i]);
}

// ---------------------------------------------------------------------------
// prep_kv: ONE launch, two independent jobs that both depend only on the QKV
// GEMM: (a) K-cache RoPE (fp32 in place + bf16 copy), (b) V^T panel prep.
// (Q-RoPE is fused into flash6's prologue -- Qb round-trip eliminated.)
// ---------------------------------------------------------------------------
__global__ __launch_bounds__(256) void prep_kv(const float* __restrict__ Vin,
                                               short* __restrict__ Vout,
                                               float* Kc, short* __restrict__ Kb) {
    __shared__ float t[32][33];
    const int bid = blockIdx.x;
    if (bid < 2048) {
        // K rope: tid = row*128 + kvh*32 + j
        const int tid = bid * 256 + threadIdx.x;
        const int j = tid & 31;
        const int kvh = (tid >> 5) & 3;
        const int row = tid >> 7;
        const int trow = row & (SEQ - 1), b = row >> 11;
        const float inv = expf(-(float)j * 0.2878231366f);
        float s, c;
        sincosf((float)trow * inv, &s, &c);
        const long off = ((long)(b * NKV + kvh) * SEQ + trow) << 6;
        float* p = Kc + off;
        const float x1 = p[j], x2 = p[j + 32];
        const float y1 = x1 * c - x2 * s, y2 = x2 * c + x1 * s;
        p[j] = y1;
        p[j + 32] = y2;
        Kb[off + j] = f2bs(y1);
        Kb[off + j + 32] = f2bs(y2);
    } else {
        // V^T: out_v (B,NKV,SEQ,64) fp32 -> Vt[bkv][t>>6][d][t&63] bf16
        const int b2 = bid - 2048;
        const int tx = b2 & 63, dy = (b2 >> 6) & 1;
        const long bkv = b2 >> 7;
        const float* ip = Vin + bkv * SEQ * DHEAD;
        short* op = Vout + bkv * DHEAD * SEQ;
        const int t0 = tx * 32, d0 = dy * 32;
        const int x = threadIdx.x & 31, y = threadIdx.x >> 5;
#pragma unroll
        for (int i = 0; i < 32; i += 8)
            t[y + i][x] = ip[(long)(t0 + y + i) * DHEAD + d0 + x];
        __syncthreads();
        const int pan = t0 >> 6, tin = t0 & 63;  // uniform for x<32
#pragma unroll
        for (int i = 0; i < 32; i += 8)
            op[(long)pan * 4096 + (d0 + y + i) * 64 + tin + x] = f2bs(t[x][y + i]);
    }
}

// ---------------------------------------------------------------------------
// MFMA GEMM (TN): C = A[M,K] @ Bt[N,K]^T, fp32 accumulate.
// MODE 0: plain fp32 C.  MODE 1: 3-way split (Q / K cache / V cache).
// ---------------------------------------------------------------------------
#define LST 40

template <typename TA, int MODE>
__global__ __launch_bounds__(256) void gemm_tn(const TA* __restrict__ A,
                                               const short* __restrict__ Bt,
                                               float* __restrict__ Cq,
                                               float* __restrict__ Ck,
                                               float* __restrict__ Cv,
                                               int M, int N, int K) {
    __shared__ short As_[128 * LST];
    __shared__ short Bs_[128 * LST];
    const int tid = threadIdx.x;
    const int lane = tid & 63, w = tid >> 6;
    const int m_ = lane & 15, quad = lane >> 4;
    const int wm = w >> 1, wn = w & 1;
    const long bm = (long)blockIdx.y * 128, bn = (long)blockIdx.x * 128;
    const int sr = tid >> 1, sh = (tid & 1) * 16;

    f32x4 acc[4][4];
#pragma unroll
    for (int i = 0; i < 4; ++i)
#pragma unroll
        for (int j = 0; j < 4; ++j) acc[i][j] = (f32x4){0.f, 0.f, 0.f, 0.f};

    for (int k0 = 0; k0 < K; k0 += 32) {
        short av[16], bv[16];
        if (sizeof(TA) == 4) {
            const float* ap = (const float*)A + (bm + sr) * K + k0 + sh;
            float ff[16];
#pragma unroll
            for (int i = 0; i < 4; ++i) *(float4*)&ff[4 * i] = ((const float4*)ap)[i];
#pragma unroll
            for (int i = 0; i < 16; ++i) av[i] = f2bs(ff[i]);
        } else {
            const short* ap = (const short*)A + (bm + sr) * K + k0 + sh;
            *(uint4*)&av[0] = ((const uint4*)ap)[0];
            *(uint4*)&av[8] = ((const uint4*)ap)[1];
        }
        {
            const short* bp = Bt + (bn + sr) * K + k0 + sh;
            *(uint4*)&bv[0] = ((const uint4*)bp)[0];
            *(uint4*)&bv[8] = ((const uint4*)bp)[1];
        }
        __syncthreads();
        short* ad = &As_[sr * LST + sh];
        short* bd = &Bs_[sr * LST + sh];
#pragma unroll
        for (int i = 0; i < 4; ++i) {
            ((uint2*)ad)[i] = ((uint2*)av)[i];
            ((uint2*)bd)[i] = ((uint2*)bv)[i];
        }
        __syncthreads();

        short8 af[4], bf[4];
#pragma unroll
        for (int i = 0; i < 4; ++i)
            af[i] = *(const short8*)&As_[(wm * 64 + i * 16 + m_) * LST + quad * 8];
#pragma unroll
        for (int j = 0; j < 4; ++j)
            bf[j] = *(const short8*)&Bs_[(wn * 64 + j * 16 + m_) * LST + quad * 8];
#pragma unroll
        for (int i = 0; i < 4; ++i)
#pragma unroll
            for (int j = 0; j < 4; ++j)
                acc[i][j] = __builtin_amdgcn_mfma_f32_16x16x32_bf16(af[i], bf[j], acc[i][j], 0, 0, 0);
    }

#pragma unroll
    for (int i = 0; i < 4; ++i) {
        const int row0 = (int)bm + wm * 64 + i * 16 + quad * 4;
#pragma unroll
        for (int j = 0; j < 4; ++j) {
            const int col = (int)bn + wn * 64 + j * 16 + m_;
#pragma unroll
            for (int r = 0; r < 4; ++r) {
                const int rw = row0 + r;
                const float val = acc[i][j][r];
                if (MODE == 1) {
                    if (col < DMODEL) {
                        Cq[(long)rw * DMODEL + col] = val;
                    } else {
                        const int c2 = col - DMODEL;
                        const int hh = (c2 >> 6) & 3, d = c2 & 63;
                        long oidx = (((long)((rw >> 11) * NKV + hh) * SEQ + (rw & (SEQ - 1))) << 6) | d;
                        ((c2 >> 8) ? Cv : Ck)[oidx] = val;
                    }
                } else {
                    Cq[(long)rw * N + col] = val;
                }
            }
        }
    }
}

// ---------------------------------------------------------------------------
// Flash v10 = v9 + fused Q-RoPE: Q read as fp32 straight from the QKV-GEMM
// output; rope applied in-prologue (8 sincosf/lane, once per block; identical
// arithmetic to the old rope_f Q path incl. the folded 1/8 scale). The Qb
// bf16 round-trip (12.6 MB R + 6.3 MB W + 6.3 MB R) and 3/4 of the old
// rope_f's threads are gone. Staging: async global_load_lds DMA with
// pre-swizzled global source (linear LDS dest), 1-tile prefetch, vmcnt(0) +
// raw s_barrier per tile (never a lgkm drain at barriers).
// ---------------------------------------------------------------------------
__global__ __launch_bounds__(384) void flash6(
    const float* __restrict__ Qf, const short* __restrict__ Kb,
    const short* __restrict__ Vt, short* __restrict__ ATT) {
    __shared__ short Kbuf[2][64 * 64];
    __shared__ short Vbuf[2][64 * 64];
    __shared__ short Pl[6][16 * 64];
    const int tid = threadIdx.x;
    const int w = tid >> 6, lane = tid & 63;
    const int m_ = lane & 15, quad = lane >> 4;
    const int sw = m_ & 7;
    const int bkv = blockIdx.x >> 6;
    const int t0 = (63 - (blockIdx.x & 63)) << 5;   // heavy blocks first
    const int b = bkv >> 2, kvh = bkv & 3;
    const int h = kvh * 3 + (w >> 1);
    const int qg = w & 1;
    const int trw = t0 + (qg << 4);
    const int tq = trw + m_;       // this lane's q-row
    const long kgb = ((long)bkv * SEQ) << 6;        // Kb base (shorts)
    const long vgb = (long)bkv * SEQ * DHEAD;       // Vt base (shorts)

    // per-lane inverse-swizzled source offset (shorts): row=lane>>3 within
    // 8-row chunk, 16B-group = (lane&7) ^ (lane>>3). LDS dest is linear.
    const int soff = ((lane >> 3) << 6) + (((lane & 7) ^ (lane >> 3)) << 3);

    // Q fp32 load + fused RoPE -> bf16 B-frags (scale 1/8 folded, as before)
    short8 qf0, qf1;
    {
        const float* qpf = Qf + (long)(b * SEQ + tq) * DMODEL + h * DHEAD + quad * 8;
        float xx[8], yy[8];
        *(float4*)&xx[0] = ((const float4*)qpf)[0];
        *(float4*)&xx[4] = ((const float4*)qpf)[1];
        *(float4*)&yy[0] = ((const float4*)(qpf + 32))[0];
        *(float4*)&yy[4] = ((const float4*)(qpf + 32))[1];
#pragma unroll
        for (int jj = 0; jj < 8; ++jj) {
            const int j = quad * 8 + jj;
            const float inv = expf(-(float)j * 0.2878231366f);
            float s_, c_;
            sincosf((float)tq * inv, &s_, &c_);
            qf0[jj] = f2bs((xx[jj] * c_ - yy[jj] * s_) * 0.125f);
            qf1[jj] = f2bs((yy[jj] * c_ + xx[jj] * s_) * 0.125f);
        }
    }

    f32x4 of[4];
#pragma unroll
    for (int i = 0; i < 4; ++i) of[i] = (f32x4){0.f, 0.f, 0.f, 0.f};
    float mr = -1e30f, lr = 0.f;

    int wlo = t0 - (WIN - 1);      // FIRST row's window floor
    if (wlo < GLB) wlo = GLB;
    wlo &= ~63;
    const int nwin = (t0 + 31 >= wlo) ? (((t0 + 31 - wlo) >> 6) + 1) : 0;
    const int ntile = 1 + nwin;
    auto kb_of = [&](int j) { return (j == 0) ? 0 : (wlo + ((j - 1) << 6)); };

    // 16 chunks of 1KB (K rows 8c..8c+7 | V d-rows 8c..8c+7); wave w takes
    // chunks {w, w+6, w+12} -- wave-uniform control, no register arrays.
    auto stage = [&](int kb, int bs) {
#pragma unroll
        for (int r = 0; r < 3; ++r) {
            const int ch = w + 6 * r;
            if (ch < 8) {
                cp16(Kb + kgb + ((long)(kb + (ch << 3)) << 6) + soff,
                     &Kbuf[bs][ch << 9]);
            } else if (ch < 16) {
                const int cv = ch - 8;
                cp16(Vt + vgb + (((long)kb >> 6) << 12) + (cv << 9) + soff,
                     &Vbuf[bs][cv << 9]);
            }
        }
    };

    stage(kb_of(0), 0);
    asm volatile("s_waitcnt vmcnt(0)" ::: "memory");
    asm volatile("s_barrier" ::: "memory");

    for (int tI = 0; tI < ntile; ++tI) {
        const int kb = kb_of(tI);
        const int bs = tI & 1;
        if (tI + 1 < ntile) stage(kb_of(tI + 1), bs ^ 1);

        // frags from LDS (swizzled reads; conflict-light)
        short8 kf[8], vf[8];
#pragma unroll
        for (int st = 0; st < 4; ++st)
#pragma unroll
            for (int hh = 0; hh < 2; ++hh)
                kf[st * 2 + hh] = *(const short8*)&Kbuf[bs][(st * 16 + m_) * 64 + (((hh * 4 + quad) ^ sw) << 3)];
#pragma unroll
        for (int dt = 0; dt < 4; ++dt)
#pragma unroll
            for (int kh = 0; kh < 2; ++kh)
                vf[dt * 2 + kh] = *(const short8*)&Vbuf[bs][(dt * 16 + m_) * 64 + (((kh * 4 + quad) ^ sw) << 3)];

        // S^T = K Q^T
        f32x4 s[4];
        __builtin_amdgcn_s_setprio(1);
#pragma unroll
        for (int st = 0; st < 4; ++st) {
            f32x4 a = (f32x4){0.f, 0.f, 0.f, 0.f};
            a = __builtin_amdgcn_mfma_f32_16x16x32_bf16(kf[st * 2 + 0], qf0, a, 0, 0, 0);
            a = __builtin_amdgcn_mfma_f32_16x16x32_bf16(kf[st * 2 + 1], qf1, a, 0, 0, 0);
            s[st] = a;
        }
        __builtin_amdgcn_s_setprio(0);

        const bool fully = (kb + 63 <= trw) &&
                           ((kb >= trw + 16 - WIN) || (kb + 63 < GLB) || (trw + 15 < GLB));
        if (!fully) {
#pragma unroll
            for (int st = 0; st < 4; ++st) {
#pragma unroll
                for (int r = 0; r < 4; ++r) {
                    const int key = kb + st * 16 + quad * 4 + r;
                    const bool ok = (key <= tq) && ((key > tq - WIN) || (key < GLB) || (tq < GLB));
                    if (!ok) s[st][r] = -1e30f;
                }
            }
        }

        // online softmax (per-lane; 2 shuffles across quad replicas)
        float tm = -1e30f;
#pragma unroll
        for (int st = 0; st < 4; ++st)
#pragma unroll
            for (int r = 0; r < 4; ++r) tm = fmaxf(tm, s[st][r]);
        tm = fmaxf(tm, __shfl_xor(tm, 16, 64));
        tm = fmaxf(tm, __shfl_xor(tm, 32, 64));
        // defer-rescale: alpha==1 exactly when max doesn't grow -> skip pass
        if (!__all(tm <= mr)) {
            const float mnew = fmaxf(mr, tm);
            const float alpha = __expf(mr - mnew);
            mr = mnew;
            lr *= alpha;
#pragma unroll
            for (int dt = 0; dt < 4; ++dt)
#pragma unroll
                for (int r = 0; r < 4; ++r) of[dt][r] *= alpha;
        }
        float rs = 0.f;
#pragma unroll
        for (int st = 0; st < 4; ++st) {
            float p0 = __expf(s[st][0] - mr);
            float p1 = __expf(s[st][1] - mr);
            float p2 = __expf(s[st][2] - mr);
            float p3 = __expf(s[st][3] - mr);
            rs += (p0 + p1) + (p2 + p3);
            union { short sh[4]; unsigned long long u; } pk;
            pk.sh[0] = f2bs(p0); pk.sh[1] = f2bs(p1);
            pk.sh[2] = f2bs(p2); pk.sh[3] = f2bs(p3);
            // swizzled 8B write: row m_, short-col st*16+quad*4
            *(unsigned long long*)&Pl[w][m_ * 64 + (((st * 2 + (quad >> 1)) ^ sw) << 3) + ((quad & 1) << 2)] = pk.u;
        }
        rs += __shfl_xor(rs, 16, 64);
        rs += __shfl_xor(rs, 32, 64);
        lr += rs;

        // P^T B-frags via per-wave LDS (same wave writes+reads: no barrier)
        short8 pf[2];
#pragma unroll
        for (int kh = 0; kh < 2; ++kh)
            pf[kh] = *(const short8*)&Pl[w][m_ * 64 + (((kh * 4 + quad) ^ sw) << 3)];

        // O^T += V^T P^T
        __builtin_amdgcn_s_setprio(1);
#pragma unroll
        for (int dt = 0; dt < 4; ++dt) {
            of[dt] = __builtin_amdgcn_mfma_f32_16x16x32_bf16(vf[dt * 2 + 0], pf[0], of[dt], 0, 0, 0);
            of[dt] = __builtin_amdgcn_mfma_f32_16x16x32_bf16(vf[dt * 2 + 1], pf[1], of[dt], 0, 0, 0);
        }
        __builtin_amdgcn_s_setprio(0);

        // drain prefetch DMAs + barrier (skip after last tile)
        if (tI + 1 < ntile) {
            asm volatile("s_waitcnt vmcnt(0)" ::: "memory");
            asm volatile("s_barrier" ::: "memory");
        }
    }

    // epilogue
    const float inv = 1.0f / lr;
    short* op = ATT + (long)(b * SEQ + tq) * DMODEL + h * DHEAD + quad * 4;
#pragma unroll
    for (int dt = 0; dt < 4; ++dt) {
        union { short sh[4]; unsigned long long u; } pk;
#pragma unroll
        for (int r = 0; r < 4; ++r) pk.sh[r] = f2bs(of[dt][r] * inv);
        *(unsigned long long*)(op + dt * 16) = pk.u;
    }
}

// ---------------------------------------------------------------------------
extern "C" void kernel_launch(void* const* d_in, const int* in_sizes, int n_in,
                              void* d_out, int out_size, void* d_ws, size_t ws_size,
                              hipStream_t stream) {
    const float* x = (const float*)d_in[0];
    const float* wq = (const float*)d_in[1];
    const float* wk = (const float*)d_in[2];
    const float* wv = (const float*)d_in[3];
    const float* wo = (const float*)d_in[4];
    float* out = (float*)d_out;
    float* out_k = out + (long)ROWS * DMODEL;
    float* out_v = out_k + (long)BATCH * NKV * SEQ * DHEAD;

    // ws (shorts), 11.125 MiB: region A: wqkvT -> ATTb (sequential lifetimes)
    short* regA = (short*)d_ws;
    short* wqkvT = regA;
    short* ATTb = regA;
    short* woT = regA + (long)ROWS * DMODEL;
    short* KbB = woT + (long)DMODEL * DMODEL;
    short* VtB = KbB + (long)BATCH * NKV * SEQ * DHEAD;

    transp_all<<<1536, 256, 0, stream>>>(wq, wk, wv, wo, wqkvT, woT);
    gemm_tn<float, 1><<<dim3((DMODEL + 2 * NKV * DHEAD) / 128, ROWS / 128), 256, 0, stream>>>(
        x, wqkvT, out, out_k, out_v, ROWS, DMODEL + 2 * NKV * DHEAD, DMODEL);
    prep_kv<<<2048 + 1024, 256, 0, stream>>>(out_v, VtB, out_k, KbB);
    flash6<<<BATCH * NKV * (SEQ / 32), 384, 0, stream>>>(out, KbB, VtB, ATTb);
    gemm_tn<short, 0><<<dim3(DMODEL / 128, ROWS / 128), 256, 0, stream>>>(
        ATTb, woT, out, nullptr, nullptr, ROWS, DMODEL, DMODEL);
}

// Round 5
// 138.326 us; speedup vs baseline: 1.4716x; 1.1657x over previous
//
#include <hip/hip_runtime.h>
#include <hip/hip_bf16.h>

#define BATCH 2
#define SEQ 2048
#define DMODEL 768
#define NHEADS 12
#define NKV 4
#define DHEAD 64
#define WIN 512
#define GLB 64
#define ROWS (BATCH * SEQ)  // 4096

typedef short short8 __attribute__((ext_vector_type(8)));
typedef float f32x4 __attribute__((ext_vector_type(4)));

// fp32 -> bf16 bits, round-to-nearest-even (finite inputs only)
__device__ inline short f2bs(float f) {
    unsigned u = __float_as_uint(f);
    return (short)((u + 0x7fffu + ((u >> 16) & 1u)) >> 16);
}

// async global->LDS DMA, 16B/lane: LDS dest = wave-uniform base + lane*16.
__device__ inline void cp16(const short* g, short* l) {
    __builtin_amdgcn_global_load_lds(
        (const __attribute__((address_space(1))) unsigned int*)g,
        (__attribute__((address_space(3))) unsigned int*)l, 16, 0, 0);
}

// ---------------------------------------------------------------------------
// Weight transposes (blocks 0..1535) + x fp32->bf16 convert (blocks 1536..3071).
// ---------------------------------------------------------------------------
__global__ __launch_bounds__(256) void transp_all(
    const float* __restrict__ wq, const float* __restrict__ wk,
    const float* __restrict__ wv, const float* __restrict__ wo,
    short* __restrict__ wqkvT, short* __restrict__ woT,
    const float* __restrict__ x, short* __restrict__ xb) {
    __shared__ float t[32][33];
    int bid = blockIdx.x;
    if (bid >= 1536) {
        // x convert: 1536 blocks x 256 thr x 8 elems = 3,145,728 = ROWS*DMODEL
        const long i = ((long)(bid - 1536) * 256 + threadIdx.x) * 8;
        float ff[8];
        *(float4*)&ff[0] = ((const float4*)(x + i))[0];
        *(float4*)&ff[4] = ((const float4*)(x + i))[1];
        short8 o;
#pragma unroll
        for (int j = 0; j < 8; ++j) o[j] = f2bs(ff[j]);
        *(short8*)(xb + i) = o;
        return;
    }
    const float* src; short* dst; int N;
    if (bid < 576)      { src = wq; dst = wqkvT; N = DMODEL; }
    else if (bid < 768) { src = wk; dst = wqkvT + DMODEL * DMODEL; N = 256; bid -= 576; }
    else if (bid < 960) { src = wv; dst = wqkvT + (DMODEL + 256) * DMODEL; N = 256; bid -= 768; }
    else                { src = wo; dst = woT; N = DMODEL; bid -= 960; }
    const int ntx = N >> 5;
    const int k0 = (bid / ntx) << 5, n0 = (bid % ntx) << 5;
    const int x_ = threadIdx.x & 31, y = threadIdx.x >> 5;
#pragma unroll
    for (int i = 0; i < 32; i += 8)
        t[y + i][x_] = src[(long)(k0 + y + i) * N + n0 + x_];
    __syncthreads();
#pragma unroll
    for (int i = 0; i < 32; i += 8)
        dst[(long)(n0 + y + i) * DMODEL + k0 + x_] = f2bs(t[x_][y + i]);
}

// ---------------------------------------------------------------------------
// prep_kv: (a) K-cache RoPE (fp32 in place + bf16 copy), (b) V^T panel prep.
// ---------------------------------------------------------------------------
__global__ __launch_bounds__(256) void prep_kv(const float* __restrict__ Vin,
                                               short* __restrict__ Vout,
                                               float* Kc, short* __restrict__ Kb) {
    __shared__ float t[32][33];
    const int bid = blockIdx.x;
    if (bid < 2048) {
        const int tid = bid * 256 + threadIdx.x;
        const int j = tid & 31;
        const int kvh = (tid >> 5) & 3;
        const int row = tid >> 7;
        const int trow = row & (SEQ - 1), b = row >> 11;
        const float inv = expf(-(float)j * 0.2878231366f);
        float s, c;
        sincosf((float)trow * inv, &s, &c);
        const long off = ((long)(b * NKV + kvh) * SEQ + trow) << 6;
        float* p = Kc + off;
        const float x1 = p[j], x2 = p[j + 32];
        const float y1 = x1 * c - x2 * s, y2 = x2 * c + x1 * s;
        p[j] = y1;
        p[j + 32] = y2;
        Kb[off + j] = f2bs(y1);
        Kb[off + j + 32] = f2bs(y2);
    } else {
        const int b2 = bid - 2048;
        const int tx = b2 & 63, dy = (b2 >> 6) & 1;
        const long bkv = b2 >> 7;
        const float* ip = Vin + bkv * SEQ * DHEAD;
        short* op = Vout + bkv * DHEAD * SEQ;
        const int t0 = tx * 32, d0 = dy * 32;
        const int x = threadIdx.x & 31, y = threadIdx.x >> 5;
#pragma unroll
        for (int i = 0; i < 32; i += 8)
            t[y + i][x] = ip[(long)(t0 + y + i) * DHEAD + d0 + x];
        __syncthreads();
        const int pan = t0 >> 6, tin = t0 & 63;  // uniform for x<32
#pragma unroll
        for (int i = 0; i < 32; i += 8)
            op[(long)pan * 4096 + (d0 + y + i) * 64 + tin + x] = f2bs(t[x][y + i]);
    }
}

// ---------------------------------------------------------------------------
// MFMA GEMM (TN), v2: bf16 A and B, staged via async global_load_lds DMA with
// pre-swizzled global source (linear LDS dest, XOR-swizzled reads -- the
// flash6-proven pattern). BK=64 double-buffered (64 KB LDS), 1-step prefetch,
// vmcnt(0) + raw s_barrier once per K-step (12 barriers vs 48), setprio
// around the MFMA cluster. MODE 0: plain fp32 C. MODE 1: Q/K/V 3-way split.
// ---------------------------------------------------------------------------
template <int MODE>
__global__ __launch_bounds__(256) void gemm_tn(const short* __restrict__ A,
                                               const short* __restrict__ Bt,
                                               float* __restrict__ Cq,
                                               float* __restrict__ Ck,
                                               float* __restrict__ Cv,
                                               int M, int N, int K) {
    __shared__ short As_[2][128 * 64];
    __shared__ short Bs_[2][128 * 64];
    const int tid = threadIdx.x;
    const int lane = tid & 63, w = tid >> 6;
    const int m_ = lane & 15, quad = lane >> 4;
    const int sw = m_ & 7;
    const int wm = w >> 1, wn = w & 1;
    const long bm = (long)blockIdx.y * 128, bn = (long)blockIdx.x * 128;
    // per-lane inverse-swizzled source offset: row = lane>>3 (global row
    // stride K shorts), 16B-group = (lane&7) ^ (lane>>3). LDS dest linear.
    const int soff = (lane >> 3) * K + (((lane & 7) ^ (lane >> 3)) << 3);

    f32x4 acc[4][4];
#pragma unroll
    for (int i = 0; i < 4; ++i)
#pragma unroll
        for (int j = 0; j < 4; ++j) acc[i][j] = (f32x4){0.f, 0.f, 0.f, 0.f};

    // 32 chunks of 1KB per K-step (A rows 8c..8c+7 | B rows): wave w takes 8.
    auto stage = [&](int k0, int bs) {
#pragma unroll
        for (int r = 0; r < 8; ++r) {
            const int ch = (w << 3) + r;
            if (ch < 16)
                cp16(A + (bm + (ch << 3)) * K + k0 + soff, &As_[bs][ch << 9]);
            else
                cp16(Bt + (bn + ((ch - 16) << 3)) * K + k0 + soff,
                     &Bs_[bs][(ch - 16) << 9]);
        }
    };

    stage(0, 0);
    asm volatile("s_waitcnt vmcnt(0)" ::: "memory");
    asm volatile("s_barrier" ::: "memory");

    const int nk = K >> 6;
    for (int ks = 0; ks < nk; ++ks) {
        const int bs = ks & 1;
        if (ks + 1 < nk) stage((ks + 1) << 6, bs ^ 1);
#pragma unroll
        for (int kh = 0; kh < 2; ++kh) {
            short8 af[4], bf[4];
#pragma unroll
            for (int i = 0; i < 4; ++i)
                af[i] = *(const short8*)&As_[bs][(wm * 64 + i * 16 + m_) * 64 + (((kh * 4 + quad) ^ sw) << 3)];
#pragma unroll
            for (int j = 0; j < 4; ++j)
                bf[j] = *(const short8*)&Bs_[bs][(wn * 64 + j * 16 + m_) * 64 + (((kh * 4 + quad) ^ sw) << 3)];
            __builtin_amdgcn_s_setprio(1);
#pragma unroll
            for (int i = 0; i < 4; ++i)
#pragma unroll
                for (int j = 0; j < 4; ++j)
                    acc[i][j] = __builtin_amdgcn_mfma_f32_16x16x32_bf16(af[i], bf[j], acc[i][j], 0, 0, 0);
            __builtin_amdgcn_s_setprio(0);
        }
        if (ks + 1 < nk) {
            asm volatile("s_waitcnt vmcnt(0)" ::: "memory");
            asm volatile("s_barrier" ::: "memory");
        }
    }

#pragma unroll
    for (int i = 0; i < 4; ++i) {
        const int row0 = (int)bm + wm * 64 + i * 16 + quad * 4;
#pragma unroll
        for (int j = 0; j < 4; ++j) {
            const int col = (int)bn + wn * 64 + j * 16 + m_;
#pragma unroll
            for (int r = 0; r < 4; ++r) {
                const int rw = row0 + r;
                const float val = acc[i][j][r];
                if (MODE == 1) {
                    if (col < DMODEL) {
                        Cq[(long)rw * DMODEL + col] = val;
                    } else {
                        const int c2 = col - DMODEL;
                        const int hh = (c2 >> 6) & 3, d = c2 & 63;
                        long oidx = (((long)((rw >> 11) * NKV + hh) * SEQ + (rw & (SEQ - 1))) << 6) | d;
                        ((c2 >> 8) ? Cv : Ck)[oidx] = val;
                    }
                } else {
                    Cq[(long)rw * N + col] = val;
                }
            }
        }
    }
}

// ---------------------------------------------------------------------------
// Flash v10 (unchanged from R4): fused Q-RoPE prologue; async global_load_lds
// staging with pre-swizzled source; 1-tile prefetch; vmcnt(0)+raw s_barrier.
// ---------------------------------------------------------------------------
__global__ __launch_bounds__(384) void flash6(
    const float* __restrict__ Qf, const short* __restrict__ Kb,
    const short* __restrict__ Vt, short* __restrict__ ATT) {
    __shared__ short Kbuf[2][64 * 64];
    __shared__ short Vbuf[2][64 * 64];
    __shared__ short Pl[6][16 * 64];
    const int tid = threadIdx.x;
    const int w = tid >> 6, lane = tid & 63;
    const int m_ = lane & 15, quad = lane >> 4;
    const int sw = m_ & 7;
    const int bkv = blockIdx.x >> 6;
    const int t0 = (63 - (blockIdx.x & 63)) << 5;   // heavy blocks first
    const int b = bkv >> 2, kvh = bkv & 3;
    const int h = kvh * 3 + (w >> 1);
    const int qg = w & 1;
    const int trw = t0 + (qg << 4);
    const int tq = trw + m_;       // this lane's q-row
    const long kgb = ((long)bkv * SEQ) << 6;        // Kb base (shorts)
    const long vgb = (long)bkv * SEQ * DHEAD;       // Vt base (shorts)

    const int soff = ((lane >> 3) << 6) + (((lane & 7) ^ (lane >> 3)) << 3);

    // Q fp32 load + fused RoPE -> bf16 B-frags (scale 1/8 folded)
    short8 qf0, qf1;
    {
        const float* qpf = Qf + (long)(b * SEQ + tq) * DMODEL + h * DHEAD + quad * 8;
        float xx[8], yy[8];
        *(float4*)&xx[0] = ((const float4*)qpf)[0];
        *(float4*)&xx[4] = ((const float4*)qpf)[1];
        *(float4*)&yy[0] = ((const float4*)(qpf + 32))[0];
        *(float4*)&yy[4] = ((const float4*)(qpf + 32))[1];
#pragma unroll
        for (int jj = 0; jj < 8; ++jj) {
            const int j = quad * 8 + jj;
            const float inv = expf(-(float)j * 0.2878231366f);
            float s_, c_;
            sincosf((float)tq * inv, &s_, &c_);
            qf0[jj] = f2bs((xx[jj] * c_ - yy[jj] * s_) * 0.125f);
            qf1[jj] = f2bs((yy[jj] * c_ + xx[jj] * s_) * 0.125f);
        }
    }

    f32x4 of[4];
#pragma unroll
    for (int i = 0; i < 4; ++i) of[i] = (f32x4){0.f, 0.f, 0.f, 0.f};
    float mr = -1e30f, lr = 0.f;

    int wlo = t0 - (WIN - 1);      // FIRST row's window floor
    if (wlo < GLB) wlo = GLB;
    wlo &= ~63;
    const int nwin = (t0 + 31 >= wlo) ? (((t0 + 31 - wlo) >> 6) + 1) : 0;
    const int ntile = 1 + nwin;
    auto kb_of = [&](int j) { return (j == 0) ? 0 : (wlo + ((j - 1) << 6)); };

    auto stage = [&](int kb, int bs) {
#pragma unroll
        for (int r = 0; r < 3; ++r) {
            const int ch = w + 6 * r;
            if (ch < 8) {
                cp16(Kb + kgb + ((long)(kb + (ch << 3)) << 6) + soff,
                     &Kbuf[bs][ch << 9]);
            } else if (ch < 16) {
                const int cv = ch - 8;
                cp16(Vt + vgb + (((long)kb >> 6) << 12) + (cv << 9) + soff,
                     &Vbuf[bs][cv << 9]);
            }
        }
    };

    stage(kb_of(0), 0);
    asm volatile("s_waitcnt vmcnt(0)" ::: "memory");
    asm volatile("s_barrier" ::: "memory");

    for (int tI = 0; tI < ntile; ++tI) {
        const int kb = kb_of(tI);
        const int bs = tI & 1;
        if (tI + 1 < ntile) stage(kb_of(tI + 1), bs ^ 1);

        short8 kf[8], vf[8];
#pragma unroll
        for (int st = 0; st < 4; ++st)
#pragma unroll
            for (int hh = 0; hh < 2; ++hh)
                kf[st * 2 + hh] = *(const short8*)&Kbuf[bs][(st * 16 + m_) * 64 + (((hh * 4 + quad) ^ sw) << 3)];
#pragma unroll
        for (int dt = 0; dt < 4; ++dt)
#pragma unroll
            for (int kh = 0; kh < 2; ++kh)
                vf[dt * 2 + kh] = *(const short8*)&Vbuf[bs][(dt * 16 + m_) * 64 + (((kh * 4 + quad) ^ sw) << 3)];

        // S^T = K Q^T
        f32x4 s[4];
        __builtin_amdgcn_s_setprio(1);
#pragma unroll
        for (int st = 0; st < 4; ++st) {
            f32x4 a = (f32x4){0.f, 0.f, 0.f, 0.f};
            a = __builtin_amdgcn_mfma_f32_16x16x32_bf16(kf[st * 2 + 0], qf0, a, 0, 0, 0);
            a = __builtin_amdgcn_mfma_f32_16x16x32_bf16(kf[st * 2 + 1], qf1, a, 0, 0, 0);
            s[st] = a;
        }
        __builtin_amdgcn_s_setprio(0);

        const bool fully = (kb + 63 <= trw) &&
                           ((kb >= trw + 16 - WIN) || (kb + 63 < GLB) || (trw + 15 < GLB));
        if (!fully) {
#pragma unroll
            for (int st = 0; st < 4; ++st) {
#pragma unroll
                for (int r = 0; r < 4; ++r) {
                    const int key = kb + st * 16 + quad * 4 + r;
                    const bool ok = (key <= tq) && ((key > tq - WIN) || (key < GLB) || (tq < GLB));
                    if (!ok) s[st][r] = -1e30f;
                }
            }
        }

        float tm = -1e30f;
#pragma unroll
        for (int st = 0; st < 4; ++st)
#pragma unroll
            for (int r = 0; r < 4; ++r) tm = fmaxf(tm, s[st][r]);
        tm = fmaxf(tm, __shfl_xor(tm, 16, 64));
        tm = fmaxf(tm, __shfl_xor(tm, 32, 64));
        if (!__all(tm <= mr)) {
            const float mnew = fmaxf(mr, tm);
            const float alpha = __expf(mr - mnew);
            mr = mnew;
            lr *= alpha;
#pragma unroll
            for (int dt = 0; dt < 4; ++dt)
#pragma unroll
                for (int r = 0; r < 4; ++r) of[dt][r] *= alpha;
        }
        float rs = 0.f;
#pragma unroll
        for (int st = 0; st < 4; ++st) {
            float p0 = __expf(s[st][0] - mr);
            float p1 = __expf(s[st][1] - mr);
            float p2 = __expf(s[st][2] - mr);
            float p3 = __expf(s[st][3] - mr);
            rs += (p0 + p1) + (p2 + p3);
            union { short sh[4]; unsigned long long u; } pk;
            pk.sh[0] = f2bs(p0); pk.sh[1] = f2bs(p1);
            pk.sh[2] = f2bs(p2); pk.sh[3] = f2bs(p3);
            *(unsigned long long*)&Pl[w][m_ * 64 + (((st * 2 + (quad >> 1)) ^ sw) << 3) + ((quad & 1) << 2)] = pk.u;
        }
        rs += __shfl_xor(rs, 16, 64);
        rs += __shfl_xor(rs, 32, 64);
        lr += rs;

        short8 pf[2];
#pragma unroll
        for (int kh = 0; kh < 2; ++kh)
            pf[kh] = *(const short8*)&Pl[w][m_ * 64 + (((kh * 4 + quad) ^ sw) << 3)];

        __builtin_amdgcn_s_setprio(1);
#pragma unroll
        for (int dt = 0; dt < 4; ++dt) {
            of[dt] = __builtin_amdgcn_mfma_f32_16x16x32_bf16(vf[dt * 2 + 0], pf[0], of[dt], 0, 0, 0);
            of[dt] = __builtin_amdgcn_mfma_f32_16x16x32_bf16(vf[dt * 2 + 1], pf[1], of[dt], 0, 0, 0);
        }
        __builtin_amdgcn_s_setprio(0);

        if (tI + 1 < ntile) {
            asm volatile("s_waitcnt vmcnt(0)" ::: "memory");
            asm volatile("s_barrier" ::: "memory");
        }
    }

    const float inv = 1.0f / lr;
    short* op = ATT + (long)(b * SEQ + tq) * DMODEL + h * DHEAD + quad * 4;
#pragma unroll
    for (int dt = 0; dt < 4; ++dt) {
        union { short sh[4]; unsigned long long u; } pk;
#pragma unroll
        for (int r = 0; r < 4; ++r) pk.sh[r] = f2bs(of[dt][r] * inv);
        *(unsigned long long*)(op + dt * 16) = pk.u;
    }
}

// ---------------------------------------------------------------------------
extern "C" void kernel_launch(void* const* d_in, const int* in_sizes, int n_in,
                              void* d_out, int out_size, void* d_ws, size_t ws_size,
                              hipStream_t stream) {
    const float* x = (const float*)d_in[0];
    const float* wq = (const float*)d_in[1];
    const float* wk = (const float*)d_in[2];
    const float* wv = (const float*)d_in[3];
    const float* wo = (const float*)d_in[4];
    float* out = (float*)d_out;
    float* out_k = out + (long)ROWS * DMODEL;
    float* out_v = out_k + (long)BATCH * NKV * SEQ * DHEAD;

    // ws (shorts), 17.125 MiB used (ws is 256 MiB per harness fill):
    // regA: wqkvT -> ATTb (sequential lifetimes) | woT | KbB | VtB | xb
    short* regA = (short*)d_ws;
    short* wqkvT = regA;
    short* ATTb = regA;
    short* woT = regA + (long)ROWS * DMODEL;
    short* KbB = woT + (long)DMODEL * DMODEL;
    short* VtB = KbB + (long)BATCH * NKV * SEQ * DHEAD;
    short* xb = VtB + (long)BATCH * NKV * SEQ * DHEAD;

    transp_all<<<3072, 256, 0, stream>>>(wq, wk, wv, wo, wqkvT, woT, x, xb);
    gemm_tn<1><<<dim3((DMODEL + 2 * NKV * DHEAD) / 128, ROWS / 128), 256, 0, stream>>>(
        xb, wqkvT, out, out_k, out_v, ROWS, DMODEL + 2 * NKV * DHEAD, DMODEL);
    prep_kv<<<2048 + 1024, 256, 0, stream>>>(out_v, VtB, out_k, KbB);
    flash6<<<BATCH * NKV * (SEQ / 32), 384, 0, stream>>>(out, KbB, VtB, ATTb);
    gemm_tn<0><<<dim3(DMODEL / 128, ROWS / 128), 256, 0, stream>>>(
        ATTb, woT, out, nullptr, nullptr, ROWS, DMODEL, DMODEL);
}

// Round 6
// 135.245 us; speedup vs baseline: 1.5052x; 1.0228x over previous
//
#include <hip/hip_runtime.h>
#include <hip/hip_bf16.h>

#define BATCH 2
#define SEQ 2048
#define DMODEL 768
#define NHEADS 12
#define NKV 4
#define DHEAD 64
#define WIN 512
#define GLB 64
#define ROWS (BATCH * SEQ)  // 4096

typedef short short8 __attribute__((ext_vector_type(8)));
typedef float f32x4 __attribute__((ext_vector_type(4)));

// fp32 -> bf16 bits, round-to-nearest-even (finite inputs only)
__device__ inline short f2bs(float f) {
    unsigned u = __float_as_uint(f);
    return (short)((u + 0x7fffu + ((u >> 16) & 1u)) >> 16);
}

// async global->LDS DMA, 16B/lane: LDS dest = wave-uniform base + lane*16.
__device__ inline void cp16(const short* g, short* l) {
    __builtin_amdgcn_global_load_lds(
        (const __attribute__((address_space(1))) unsigned int*)g,
        (__attribute__((address_space(3))) unsigned int*)l, 16, 0, 0);
}

// ---------------------------------------------------------------------------
// Weight transposes (blocks 0..1535) + x fp32->bf16 convert (blocks 1536..3071).
// ---------------------------------------------------------------------------
__global__ __launch_bounds__(256) void transp_all(
    const float* __restrict__ wq, const float* __restrict__ wk,
    const float* __restrict__ wv, const float* __restrict__ wo,
    short* __restrict__ wqkvT, short* __restrict__ woT,
    const float* __restrict__ x, short* __restrict__ xb) {
    __shared__ float t[32][33];
    int bid = blockIdx.x;
    if (bid >= 1536) {
        const long i = ((long)(bid - 1536) * 256 + threadIdx.x) * 8;
        float ff[8];
        *(float4*)&ff[0] = ((const float4*)(x + i))[0];
        *(float4*)&ff[4] = ((const float4*)(x + i))[1];
        short8 o;
#pragma unroll
        for (int j = 0; j < 8; ++j) o[j] = f2bs(ff[j]);
        *(short8*)(xb + i) = o;
        return;
    }
    const float* src; short* dst; int N;
    if (bid < 576)      { src = wq; dst = wqkvT; N = DMODEL; }
    else if (bid < 768) { src = wk; dst = wqkvT + DMODEL * DMODEL; N = 256; bid -= 576; }
    else if (bid < 960) { src = wv; dst = wqkvT + (DMODEL + 256) * DMODEL; N = 256; bid -= 768; }
    else                { src = wo; dst = woT; N = DMODEL; bid -= 960; }
    const int ntx = N >> 5;
    const int k0 = (bid / ntx) << 5, n0 = (bid % ntx) << 5;
    const int x_ = threadIdx.x & 31, y = threadIdx.x >> 5;
#pragma unroll
    for (int i = 0; i < 32; i += 8)
        t[y + i][x_] = src[(long)(k0 + y + i) * N + n0 + x_];
    __syncthreads();
#pragma unroll
    for (int i = 0; i < 32; i += 8)
        dst[(long)(n0 + y + i) * DMODEL + k0 + x_] = f2bs(t[x_][y + i]);
}

// ---------------------------------------------------------------------------
// MFMA GEMM (TN), v3: BM=64 x BN=128 tiles (gemm1 grid 640, gemm2 384 -- TLP
// hides the per-K-step vmcnt(0) drain; 48 KB LDS -> 3 blocks/CU). Staging via
// async global_load_lds with pre-swizzled source (flash6-proven). MODE 1
// epilogue FUSES prep_kv: K-RoPE in-register (pairs (d,d+32) = acc[i][j] /
// acc[i][j+2] in the same lane; identical expf/sincosf/f2bs arithmetic on
// identical fp32 values) writing roped fp32 cache + bf16 Kb; V written as
// fp32 cache + bf16 transposed panels Vt. prep_kv kernel deleted.
// ---------------------------------------------------------------------------
template <int MODE>
__global__ __launch_bounds__(256) void gemm_tn(
    const short* __restrict__ A, const short* __restrict__ Bt,
    float* __restrict__ Cq, float* __restrict__ Ck, float* __restrict__ Cv,
    short* __restrict__ Kb, short* __restrict__ Vt, int M, int N, int K) {
    __shared__ short As_[2][64 * 64];
    __shared__ short Bs_[2][128 * 64];
    const int tid = threadIdx.x;
    const int lane = tid & 63, w = tid >> 6;
    const int m_ = lane & 15, quad = lane >> 4;
    const int sw = m_ & 7;
    const int wm = w >> 1, wn = w & 1;
    const long bm = (long)blockIdx.y * 64, bn = (long)blockIdx.x * 128;
    // per-lane inverse-swizzled source offset (linear LDS dest)
    const int soff = (lane >> 3) * K + (((lane & 7) ^ (lane >> 3)) << 3);

    f32x4 acc[2][4];
#pragma unroll
    for (int i = 0; i < 2; ++i)
#pragma unroll
        for (int j = 0; j < 4; ++j) acc[i][j] = (f32x4){0.f, 0.f, 0.f, 0.f};

    // 24 chunks of 1KB per K-step (A 8 | B 16); wave w takes 6.
    auto stage = [&](int k0, int bs) {
#pragma unroll
        for (int r = 0; r < 6; ++r) {
            const int ch = w * 6 + r;
            if (ch < 8)
                cp16(A + (bm + (ch << 3)) * K + k0 + soff, &As_[bs][ch << 9]);
            else
                cp16(Bt + (bn + ((ch - 8) << 3)) * K + k0 + soff,
                     &Bs_[bs][(ch - 8) << 9]);
        }
    };

    stage(0, 0);
    asm volatile("s_waitcnt vmcnt(0)" ::: "memory");
    asm volatile("s_barrier" ::: "memory");

    const int nk = K >> 6;
    for (int ks = 0; ks < nk; ++ks) {
        const int bs = ks & 1;
        if (ks + 1 < nk) stage((ks + 1) << 6, bs ^ 1);
#pragma unroll
        for (int kh = 0; kh < 2; ++kh) {
            short8 af[2], bf[4];
#pragma unroll
            for (int i = 0; i < 2; ++i)
                af[i] = *(const short8*)&As_[bs][(wm * 32 + i * 16 + m_) * 64 + (((kh * 4 + quad) ^ sw) << 3)];
#pragma unroll
            for (int j = 0; j < 4; ++j)
                bf[j] = *(const short8*)&Bs_[bs][(wn * 64 + j * 16 + m_) * 64 + (((kh * 4 + quad) ^ sw) << 3)];
            __builtin_amdgcn_s_setprio(1);
#pragma unroll
            for (int i = 0; i < 2; ++i)
#pragma unroll
                for (int j = 0; j < 4; ++j)
                    acc[i][j] = __builtin_amdgcn_mfma_f32_16x16x32_bf16(af[i], bf[j], acc[i][j], 0, 0, 0);
            __builtin_amdgcn_s_setprio(0);
        }
        if (ks + 1 < nk) {
            asm volatile("s_waitcnt vmcnt(0)" ::: "memory");
            asm volatile("s_barrier" ::: "memory");
        }
    }

    if (MODE == 0 || bn < DMODEL) {
        // plain fp32 store (Q region for MODE 1; whole C for MODE 0)
        const int stride = (MODE == 1) ? DMODEL : N;
#pragma unroll
        for (int i = 0; i < 2; ++i) {
            const int row0 = (int)bm + wm * 32 + i * 16 + quad * 4;
#pragma unroll
            for (int j = 0; j < 4; ++j) {
                const int col = (int)bn + wn * 64 + j * 16 + m_;
#pragma unroll
                for (int r = 0; r < 4; ++r)
                    Cq[(long)(row0 + r) * stride + col] = acc[i][j][r];
            }
        }
    } else if (bn < DMODEL + 256) {
        // K path: fused RoPE. d = j*16+m_ (j in {0,1}), partner at acc[i][j+2].
        const int kvh = ((int)(bn - DMODEL) >> 6) + wn;
#pragma unroll
        for (int i = 0; i < 2; ++i) {
            const int row0 = (int)bm + wm * 32 + i * 16 + quad * 4;
            const int t = row0 & (SEQ - 1), b = row0 >> 11;
            const long base0 = ((long)(b * NKV + kvh) * SEQ) << 6;
#pragma unroll
            for (int j = 0; j < 2; ++j) {
                const int d = j * 16 + m_;
                const float invf = expf(-(float)d * 0.2878231366f);
#pragma unroll
                for (int r = 0; r < 4; ++r) {
                    const int tt = t + r;
                    float s_, c_;
                    sincosf((float)tt * invf, &s_, &c_);
                    const float x1 = acc[i][j][r], x2 = acc[i][j + 2][r];
                    const float y1 = x1 * c_ - x2 * s_;
                    const float y2 = x2 * c_ + x1 * s_;
                    const long o = base0 + ((long)tt << 6) + d;
                    Ck[o] = y1;
                    Ck[o + 32] = y2;
                    Kb[o] = f2bs(y1);
                    Kb[o + 32] = f2bs(y2);
                }
            }
        }
    } else {
        // V path: fp32 cache + bf16 transposed panels Vt[bkv][t>>6][d][t&63]
        const int kvh = ((int)(bn - (DMODEL + 256)) >> 6) + wn;
#pragma unroll
        for (int i = 0; i < 2; ++i) {
            const int row0 = (int)bm + wm * 32 + i * 16 + quad * 4;
            const int t = row0 & (SEQ - 1), b = row0 >> 11;
            const long bkvi = (long)(b * NKV + kvh);
            const long vtbase = (bkvi << 17) + ((long)(t >> 6) << 12) + (t & 63);
#pragma unroll
            for (int j = 0; j < 4; ++j) {
                const int d = j * 16 + m_;
                union { short sh[4]; unsigned long long u; } pk;
#pragma unroll
                for (int r = 0; r < 4; ++r) {
                    const float v = acc[i][j][r];
                    Cv[((bkvi * SEQ + t + r) << 6) + d] = v;
                    pk.sh[r] = f2bs(v);
                }
                *(unsigned long long*)&Vt[vtbase + ((long)d << 6)] = pk.u;
            }
        }
    }
}

// ---------------------------------------------------------------------------
// Flash v10 (unchanged): fused Q-RoPE prologue; async global_load_lds staging
// with pre-swizzled source; 1-tile prefetch; vmcnt(0)+raw s_barrier.
// ---------------------------------------------------------------------------
__global__ __launch_bounds__(384) void flash6(
    const float* __restrict__ Qf, const short* __restrict__ Kb,
    const short* __restrict__ Vt, short* __restrict__ ATT) {
    __shared__ short Kbuf[2][64 * 64];
    __shared__ short Vbuf[2][64 * 64];
    __shared__ short Pl[6][16 * 64];
    const int tid = threadIdx.x;
    const int w = tid >> 6, lane = tid & 63;
    const int m_ = lane & 15, quad = lane >> 4;
    const int sw = m_ & 7;
    const int bkv = blockIdx.x >> 6;
    const int t0 = (63 - (blockIdx.x & 63)) << 5;   // heavy blocks first
    const int b = bkv >> 2, kvh = bkv & 3;
    const int h = kvh * 3 + (w >> 1);
    const int qg = w & 1;
    const int trw = t0 + (qg << 4);
    const int tq = trw + m_;       // this lane's q-row
    const long kgb = ((long)bkv * SEQ) << 6;        // Kb base (shorts)
    const long vgb = (long)bkv * SEQ * DHEAD;       // Vt base (shorts)

    const int soff = ((lane >> 3) << 6) + (((lane & 7) ^ (lane >> 3)) << 3);

    // Q fp32 load + fused RoPE -> bf16 B-frags (scale 1/8 folded)
    short8 qf0, qf1;
    {
        const float* qpf = Qf + (long)(b * SEQ + tq) * DMODEL + h * DHEAD + quad * 8;
        float xx[8], yy[8];
        *(float4*)&xx[0] = ((const float4*)qpf)[0];
        *(float4*)&xx[4] = ((const float4*)qpf)[1];
        *(float4*)&yy[0] = ((const float4*)(qpf + 32))[0];
        *(float4*)&yy[4] = ((const float4*)(qpf + 32))[1];
#pragma unroll
        for (int jj = 0; jj < 8; ++jj) {
            const int j = quad * 8 + jj;
            const float inv = expf(-(float)j * 0.2878231366f);
            float s_, c_;
            sincosf((float)tq * inv, &s_, &c_);
            qf0[jj] = f2bs((xx[jj] * c_ - yy[jj] * s_) * 0.125f);
            qf1[jj] = f2bs((yy[jj] * c_ + xx[jj] * s_) * 0.125f);
        }
    }

    f32x4 of[4];
#pragma unroll
    for (int i = 0; i < 4; ++i) of[i] = (f32x4){0.f, 0.f, 0.f, 0.f};
    float mr = -1e30f, lr = 0.f;

    int wlo = t0 - (WIN - 1);      // FIRST row's window floor
    if (wlo < GLB) wlo = GLB;
    wlo &= ~63;
    const int nwin = (t0 + 31 >= wlo) ? (((t0 + 31 - wlo) >> 6) + 1) : 0;
    const int ntile = 1 + nwin;
    auto kb_of = [&](int j) { return (j == 0) ? 0 : (wlo + ((j - 1) << 6)); };

    auto stage = [&](int kb, int bs) {
#pragma unroll
        for (int r = 0; r < 3; ++r) {
            const int ch = w + 6 * r;
            if (ch < 8) {
                cp16(Kb + kgb + ((long)(kb + (ch << 3)) << 6) + soff,
                     &Kbuf[bs][ch << 9]);
            } else if (ch < 16) {
                const int cv = ch - 8;
                cp16(Vt + vgb + (((long)kb >> 6) << 12) + (cv << 9) + soff,
                     &Vbuf[bs][cv << 9]);
            }
        }
    };

    stage(kb_of(0), 0);
    asm volatile("s_waitcnt vmcnt(0)" ::: "memory");
    asm volatile("s_barrier" ::: "memory");

    for (int tI = 0; tI < ntile; ++tI) {
        const int kb = kb_of(tI);
        const int bs = tI & 1;
        if (tI + 1 < ntile) stage(kb_of(tI + 1), bs ^ 1);

        short8 kf[8], vf[8];
#pragma unroll
        for (int st = 0; st < 4; ++st)
#pragma unroll
            for (int hh = 0; hh < 2; ++hh)
                kf[st * 2 + hh] = *(const short8*)&Kbuf[bs][(st * 16 + m_) * 64 + (((hh * 4 + quad) ^ sw) << 3)];
#pragma unroll
        for (int dt = 0; dt < 4; ++dt)
#pragma unroll
            for (int kh = 0; kh < 2; ++kh)
                vf[dt * 2 + kh] = *(const short8*)&Vbuf[bs][(dt * 16 + m_) * 64 + (((kh * 4 + quad) ^ sw) << 3)];

        // S^T = K Q^T
        f32x4 s[4];
        __builtin_amdgcn_s_setprio(1);
#pragma unroll
        for (int st = 0; st < 4; ++st) {
            f32x4 a = (f32x4){0.f, 0.f, 0.f, 0.f};
            a = __builtin_amdgcn_mfma_f32_16x16x32_bf16(kf[st * 2 + 0], qf0, a, 0, 0, 0);
            a = __builtin_amdgcn_mfma_f32_16x16x32_bf16(kf[st * 2 + 1], qf1, a, 0, 0, 0);
            s[st] = a;
        }
        __builtin_amdgcn_s_setprio(0);

        const bool fully = (kb + 63 <= trw) &&
                           ((kb >= trw + 16 - WIN) || (kb + 63 < GLB) || (trw + 15 < GLB));
        if (!fully) {
#pragma unroll
            for (int st = 0; st < 4; ++st) {
#pragma unroll
                for (int r = 0; r < 4; ++r) {
                    const int key = kb + st * 16 + quad * 4 + r;
                    const bool ok = (key <= tq) && ((key > tq - WIN) || (key < GLB) || (tq < GLB));
                    if (!ok) s[st][r] = -1e30f;
                }
            }
        }

        float tm = -1e30f;
#pragma unroll
        for (int st = 0; st < 4; ++st)
#pragma unroll
            for (int r = 0; r < 4; ++r) tm = fmaxf(tm, s[st][r]);
        tm = fmaxf(tm, __shfl_xor(tm, 16, 64));
        tm = fmaxf(tm, __shfl_xor(tm, 32, 64));
        if (!__all(tm <= mr)) {
            const float mnew = fmaxf(mr, tm);
            const float alpha = __expf(mr - mnew);
            mr = mnew;
            lr *= alpha;
#pragma unroll
            for (int dt = 0; dt < 4; ++dt)
#pragma unroll
                for (int r = 0; r < 4; ++r) of[dt][r] *= alpha;
        }
        float rs = 0.f;
#pragma unroll
        for (int st = 0; st < 4; ++st) {
            float p0 = __expf(s[st][0] - mr);
            float p1 = __expf(s[st][1] - mr);
            float p2 = __expf(s[st][2] - mr);
            float p3 = __expf(s[st][3] - mr);
            rs += (p0 + p1) + (p2 + p3);
            union { short sh[4]; unsigned long long u; } pk;
            pk.sh[0] = f2bs(p0); pk.sh[1] = f2bs(p1);
            pk.sh[2] = f2bs(p2); pk.sh[3] = f2bs(p3);
            *(unsigned long long*)&Pl[w][m_ * 64 + (((st * 2 + (quad >> 1)) ^ sw) << 3) + ((quad & 1) << 2)] = pk.u;
        }
        rs += __shfl_xor(rs, 16, 64);
        rs += __shfl_xor(rs, 32, 64);
        lr += rs;

        short8 pf[2];
#pragma unroll
        for (int kh = 0; kh < 2; ++kh)
            pf[kh] = *(const short8*)&Pl[w][m_ * 64 + (((kh * 4 + quad) ^ sw) << 3)];

        __builtin_amdgcn_s_setprio(1);
#pragma unroll
        for (int dt = 0; dt < 4; ++dt) {
            of[dt] = __builtin_amdgcn_mfma_f32_16x16x32_bf16(vf[dt * 2 + 0], pf[0], of[dt], 0, 0, 0);
            of[dt] = __builtin_amdgcn_mfma_f32_16x16x32_bf16(vf[dt * 2 + 1], pf[1], of[dt], 0, 0, 0);
        }
        __builtin_amdgcn_s_setprio(0);

        if (tI + 1 < ntile) {
            asm volatile("s_waitcnt vmcnt(0)" ::: "memory");
            asm volatile("s_barrier" ::: "memory");
        }
    }

    const float inv = 1.0f / lr;
    short* op = ATT + (long)(b * SEQ + tq) * DMODEL + h * DHEAD + quad * 4;
#pragma unroll
    for (int dt = 0; dt < 4; ++dt) {
        union { short sh[4]; unsigned long long u; } pk;
#pragma unroll
        for (int r = 0; r < 4; ++r) pk.sh[r] = f2bs(of[dt][r] * inv);
        *(unsigned long long*)(op + dt * 16) = pk.u;
    }
}

// ---------------------------------------------------------------------------
extern "C" void kernel_launch(void* const* d_in, const int* in_sizes, int n_in,
                              void* d_out, int out_size, void* d_ws, size_t ws_size,
                              hipStream_t stream) {
    const float* x = (const float*)d_in[0];
    const float* wq = (const float*)d_in[1];
    const float* wk = (const float*)d_in[2];
    const float* wv = (const float*)d_in[3];
    const float* wo = (const float*)d_in[4];
    float* out = (float*)d_out;
    float* out_k = out + (long)ROWS * DMODEL;
    float* out_v = out_k + (long)BATCH * NKV * SEQ * DHEAD;

    // ws (shorts): regA: wqkvT -> ATTb (sequential lifetimes) | woT | KbB | VtB | xb
    short* regA = (short*)d_ws;
    short* wqkvT = regA;
    short* ATTb = regA;
    short* woT = regA + (long)ROWS * DMODEL;
    short* KbB = woT + (long)DMODEL * DMODEL;
    short* VtB = KbB + (long)BATCH * NKV * SEQ * DHEAD;
    short* xb = VtB + (long)BATCH * NKV * SEQ * DHEAD;

    transp_all<<<3072, 256, 0, stream>>>(wq, wk, wv, wo, wqkvT, woT, x, xb);
    gemm_tn<1><<<dim3((DMODEL + 2 * NKV * DHEAD) / 128, ROWS / 64), 256, 0, stream>>>(
        xb, wqkvT, out, out_k, out_v, KbB, VtB, ROWS, DMODEL + 2 * NKV * DHEAD, DMODEL);
    flash6<<<BATCH * NKV * (SEQ / 32), 384, 0, stream>>>(out, KbB, VtB, ATTb);
    gemm_tn<0><<<dim3(DMODEL / 128, ROWS / 64), 256, 0, stream>>>(
        ATTb, woT, out, nullptr, nullptr, nullptr, nullptr, ROWS, DMODEL, DMODEL);
}